// Round 10
// baseline (3162.460 us; speedup 1.0000x reference)
//
#include <hip/hip_runtime.h>

#define DEV __device__ __forceinline__

typedef __attribute__((ext_vector_type(8))) short bf16x8;
typedef __attribute__((ext_vector_type(4))) float f32x4;
typedef __attribute__((ext_vector_type(2))) _Float16 h2_t;

typedef __attribute__((address_space(1))) const void GLDg;
typedef __attribute__((address_space(3))) void GLDl;

// ---------- constants ----------
static const int V = 50000, E = 128, H = 256, B = 32, S = 256, T = 32, FF = 4096;
static const int NCT = 391;           // ceil(50000/128)
static const int NPART = 782;         // 391 col tiles x 2 wave-cols
// workspace offsets (in floats)
static const size_t OFF_XKF  = 0;                     // S*B*4H = 8388608
static const size_t OFF_XKB  = 8388608;               // 8388608
static const size_t OFF_XKD  = 16777216;              // T*B*4H = 1048576
static const size_t OFF_HSF  = 17825792;              // S*B*H = 2097152
static const size_t OFF_HSB  = 19922944;              // 2097152
static const size_t OFF_HENC = 22020096;              // B*S*E = 1048576
static const size_t OFF_ERPF = 23068672;              // 131072 (uint)
static const size_t OFF_ERPB = 23199744;
static const size_t OFF_DRP  = 23330816;
static const size_t OFF_COMB = 23461888;              // 1024*768 ushort = 393216 floats
static const size_t OFF_FB16 = 23855104;              // 1024*4096 ushort = 2097152 floats
static const size_t OFF_LFWT = 25952256;              // 4096*768 ushort = 1572864 floats
static const size_t OFF_LVWT = 27525120;              // 50048*4096 ushort = 102498304 floats
static const size_t LVWT_FLOATS = 102498304;
static const size_t WS_NEED_BYTES = (OFF_LVWT + LVWT_FLOATS) * 4;   // ~520 MB
// scratch in the xkf region (dead after enc_lstm / before gemm respectively)
static const size_t OFF_PMAX = 0;                     // 1024*782 = 800768
static const size_t OFF_PSUM = 800768;
static const size_t OFF_TLOG = 1601536;
static const size_t OFF_NLL  = 1602560;
static const size_t OFF_CT   = 1603584;               // 31*32*256 = 253952 floats

// dynamic LDS for the fused LSTM+cvt kernel: 128KB weights + 512B h2 + 4KB zg
static const size_t ENC_LDS_BYTES = 131072 + 512 + 4096;   // 135680

// ---------- helpers ----------
DEV float sigf(float x) { return 1.0f / (1.0f + __expf(-x)); }
DEV float tanh_(float x) {
    x = fminf(fmaxf(x, -20.0f), 20.0f);
    float e = __expf(2.0f * x);
    return (e - 1.0f) / (e + 1.0f);
}
DEV unsigned short f2bf(float f) {
    unsigned int u = __builtin_bit_cast(unsigned int, f);
    u += 0x7FFFu + ((u >> 16) & 1u);
    return (unsigned short)(u >> 16);
}
DEV float bf2f(unsigned short s) {
    unsigned int u = ((unsigned int)s) << 16;
    return __builtin_bit_cast(float, u);
}
DEV float dot2u(unsigned int a, unsigned int b, float c) {
#if __has_builtin(__builtin_amdgcn_fdot2)
    return __builtin_amdgcn_fdot2(__builtin_bit_cast(h2_t, a), __builtin_bit_cast(h2_t, b), c, false);
#else
    h2_t x = __builtin_bit_cast(h2_t, a), y = __builtin_bit_cast(h2_t, b);
    return c + (float)x[0] * (float)y[0] + (float)x[1] * (float)y[1];
#endif
}

// ---------- K0: pack recurrent weights (H x 4H fp32) -> half2 dwords, COL-major [c][k2] ----------
__global__ void pack_half_k(const float* __restrict__ erf, const float* __restrict__ erb,
                            const float* __restrict__ dr,
                            unsigned int* __restrict__ pf, unsigned int* __restrict__ pb,
                            unsigned int* __restrict__ pd) {
    int id = blockIdx.x * 256 + threadIdx.x;          // 3*131072 total
    int which = id >> 17;
    int rem = id & 131071;
    const float* s = (which == 0) ? erf : (which == 1) ? erb : dr;
    unsigned int* o = (which == 0) ? pf : (which == 1) ? pb : pd;
    int cc = rem >> 7, k2 = rem & 127;                // o[cc*128+k2]
    float v0 = s[(2 * k2) * 1024 + cc];
    float v1 = s[(2 * k2 + 1) * 1024 + cc];
    h2_t h; h[0] = (_Float16)v0; h[1] = (_Float16)v1;
    o[rem] = __builtin_bit_cast(unsigned int, h);
}

// ---------- K1: gathered x@W + b  (M x 128)@(128 x 1024) ----------
__global__ __launch_bounds__(256) void xgate_kernel(const float* __restrict__ emb,
                                                    const int* __restrict__ tok_src, int dec_mode,
                                                    const float* __restrict__ wt,
                                                    const float* __restrict__ bias,
                                                    float* __restrict__ out) {
    __shared__ float Al[64][128];
    __shared__ int tk[64];
    int r0 = blockIdx.x * 64, c0b = blockIdx.y * 128;
    int tid = threadIdx.x;
    if (tid < 64) {
        int r = r0 + tid; int hi = r >> 5, b = r & 31; int token;
        if (dec_mode) token = (hi == 0) ? 2 : tok_src[b * 32 + hi];
        else          token = tok_src[b * 256 + hi];
        tk[tid] = token;
    }
    __syncthreads();
    {
        int ri = tid >> 2, cc = (tid & 3) * 32;
        const float4* src = (const float4*)&emb[(size_t)tk[ri] * 128 + cc];
        float4* dst = (float4*)&Al[ri][cc];
#pragma unroll
        for (int i = 0; i < 8; ++i) dst[i] = src[i];
    }
    __syncthreads();
    int rg = tid >> 5;
    int c = c0b + (tid & 31) * 4;
    float4 acc[8];
#pragma unroll
    for (int r = 0; r < 8; ++r) acc[r] = make_float4(0.f, 0.f, 0.f, 0.f);
    for (int k = 0; k < 128; k += 4) {
        float4 w0 = *(const float4*)&wt[(k + 0) * 1024 + c];
        float4 w1 = *(const float4*)&wt[(k + 1) * 1024 + c];
        float4 w2 = *(const float4*)&wt[(k + 2) * 1024 + c];
        float4 w3 = *(const float4*)&wt[(k + 3) * 1024 + c];
#pragma unroll
        for (int r = 0; r < 8; ++r) {
            float4 a = *(const float4*)&Al[rg * 8 + r][k];
            acc[r].x += a.x * w0.x + a.y * w1.x + a.z * w2.x + a.w * w3.x;
            acc[r].y += a.x * w0.y + a.y * w1.y + a.z * w2.y + a.w * w3.y;
            acc[r].z += a.x * w0.z + a.y * w1.z + a.z * w2.z + a.w * w3.z;
            acc[r].w += a.x * w0.w + a.y * w1.w + a.z * w2.w + a.w * w3.w;
        }
    }
    float4 b4 = *(const float4*)&bias[c];
#pragma unroll
    for (int r = 0; r < 8; ++r) {
        int row = r0 + rg * 8 + r;
        float4 v = make_float4(acc[r].x + b4.x, acc[r].y + b4.y, acc[r].z + b4.z, acc[r].w + b4.w);
        *(float4*)&out[(size_t)row * 1024 + c] = v;
    }
}

// ---------- K2: FUSED enc_lstm (64 blk) + dec_lstm (32 blk) + weight cvt (rest) ----------
// 1024 threads/block. LSTM: 1 gate-column/thread -> 24 reg uint4 (96 VGPR, FITS the
// 128-VGPR cap that 1024-thr blocks force) + 8 LDS uint4 (128KB). cvt: 256n x 128k
// tiles, 16 float4 loads/thread, pad-260 LDS, uint4 dst writes.
extern __shared__ unsigned char dyn_lds[];
__global__ __launch_bounds__(1024) void lstm_cvt_fused(
        const float* __restrict__ xkf, const float* __restrict__ xkb,
        const unsigned int* __restrict__ erpf, const unsigned int* __restrict__ erpb,
        float* __restrict__ hsf, float* __restrict__ hsb,
        const float* __restrict__ xkd, const unsigned int* __restrict__ drp,
        float* __restrict__ ct_all, unsigned short* __restrict__ comb16,
        const float* __restrict__ lfw, unsigned short* __restrict__ lfwT,
        const float* __restrict__ lvw, unsigned short* __restrict__ lvwT) {
    int bid = blockIdx.x;
    int tid = threadIdx.x;
    if (bid < 96) {
        // ----- LSTM recurrence (enc: bid<64, dec: 64..95); col = tid -----
        int is_dec = (bid >= 64);
        int dir = is_dec ? 0 : (bid >> 5);
        int row = is_dec ? (bid - 64) : (bid & 31);
        const float* xk = is_dec ? xkd : (dir ? xkb : xkf);
        const unsigned int* erp = is_dec ? drp : (dir ? erpb : erpf);
        float* hs = dir ? hsb : hsf;
        int nsteps = is_dec ? 31 : 256;
        uint4* wl = (uint4*)dyn_lds;                       // [8][1024]
        unsigned int* h2 = (unsigned int*)(dyn_lds + 131072);
        float* zg = (float*)(dyn_lds + 131072 + 512);

        const uint4* pa = (const uint4*)&erp[(size_t)tid * 128];
        uint4 wa[24];
#pragma unroll
        for (int i = 0; i < 24; ++i) wa[i] = pa[i];
        // pin weights into VGPRs (prevent re-streaming / rematerialization)
#pragma unroll
        for (int i = 0; i < 24; ++i) {
            asm volatile("" : "+v"(wa[i].x), "+v"(wa[i].y), "+v"(wa[i].z), "+v"(wa[i].w));
        }
#pragma unroll
        for (int j = 0; j < 8; ++j) wl[j * 1024 + tid] = pa[24 + j];
        if (tid < 128) h2[tid] = 0u;
        float c_reg = 0.0f;
        __syncthreads();
        int s0 = (!is_dec && dir) ? (nsteps - 1) : 0;
        float xcur = xk[(size_t)(s0 * 32 + row) * 1024 + tid];
        for (int si = 0; si < nsteps; ++si) {
            int s = (!is_dec && dir) ? (nsteps - 1 - si) : si;
            float xnext = 0.0f;
            if (si + 1 < nsteps) {
                int sn = (!is_dec && dir) ? (nsteps - 2 - si) : (si + 1);
                xnext = xk[(size_t)(sn * 32 + row) * 1024 + tid];
            }
            float acc0 = xcur;
#pragma unroll
            for (int i = 0; i < 24; ++i) {
                uint4 hv = *(const uint4*)&h2[4 * i];
                acc0 = dot2u(hv.x, wa[i].x, acc0);
                acc0 = dot2u(hv.y, wa[i].y, acc0);
                acc0 = dot2u(hv.z, wa[i].z, acc0);
                acc0 = dot2u(hv.w, wa[i].w, acc0);
            }
#pragma unroll
            for (int j = 0; j < 8; ++j) {
                uint4 hv = *(const uint4*)&h2[96 + 4 * j];
                uint4 qa = wl[j * 1024 + tid];
                acc0 = dot2u(hv.x, qa.x, acc0);
                acc0 = dot2u(hv.y, qa.y, acc0);
                acc0 = dot2u(hv.z, qa.z, acc0);
                acc0 = dot2u(hv.w, qa.w, acc0);
            }
            zg[tid] = acc0;
            __syncthreads();
            if (tid < 256) {
                float ii = zg[tid], ff = zg[tid + 256], gg = zg[tid + 512], oo = zg[tid + 768];
                c_reg = sigf(ff) * c_reg + sigf(ii) * tanh_(gg);
                float h = sigf(oo) * tanh_(c_reg);
                ((_Float16*)h2)[tid] = (_Float16)h;
                if (is_dec) {
                    ct_all[(size_t)(s * 32 + row) * 256 + tid] = c_reg;
                    comb16[(size_t)(s * 32 + row) * 768 + 512 + tid] = f2bf(c_reg);
                } else {
                    hs[(size_t)(s * 32 + row) * 256 + tid] = h;
                }
            }
            __syncthreads();
            xcur = xnext;
        }
        if (is_dec) {       // zero pad rows 992..1023 of comb16
            size_t base = (size_t)(31 * 32 + row) * 768;
            for (int j = tid; j < 768; j += 1024) comb16[base + j] = 0;
        }
    } else {
        // ----- weight convert+transpose, 256n x 128k tile per block, float4 loads -----
        const float* src; unsigned short* dst; int N, ldd, nb, kb, nmax;
        if (bid < 96 + 96) {
            int f2 = bid - 96;                    // lfw: 16 n-tiles x 6 k-tiles
            src = lfw; dst = lfwT; N = 4096; ldd = 768; nmax = 4096;
            nb = (f2 & 15) * 256; kb = (f2 >> 4) * 128;
        } else {
            int f3 = bid - 192;                   // lvw: 196 n-tiles x 32 k-tiles
            src = lvw; dst = lvwT; N = 50000; ldd = 4096; nmax = 50048;
            int nbi = f3 % 196, kbi = f3 / 196;
            nb = nbi * 256; kb = kbi * 128;
        }
        unsigned int* l32 = (unsigned int*)dyn_lds;        // [64 kpair][260 dw]
        int nl = tid & 63, kg = tid >> 6;                  // kg 0..15, each: 8 k-rows
        float4 v[8];
        if (nb + 256 <= N) {
            const float* sp = src + (size_t)(kb + kg * 8) * N + nb + nl * 4;
#pragma unroll
            for (int j = 0; j < 8; ++j) v[j] = *(const float4*)(sp + (size_t)j * N);
        } else {
#pragma unroll
            for (int j = 0; j < 8; ++j) {
                int n0 = nb + nl * 4;
                const float* rp = src + (size_t)(kb + kg * 8 + j) * N;
                v[j].x = (n0 + 0 < N) ? rp[n0 + 0] : 0.0f;
                v[j].y = (n0 + 1 < N) ? rp[n0 + 1] : 0.0f;
                v[j].z = (n0 + 2 < N) ? rp[n0 + 2] : 0.0f;
                v[j].w = (n0 + 3 < N) ? rp[n0 + 3] : 0.0f;
            }
        }
#pragma unroll
        for (int p = 0; p < 4; ++p) {           // k-pair (2p, 2p+1) within this kg's 8 rows
            unsigned int d0 = (unsigned int)f2bf(v[2 * p].x) | ((unsigned int)f2bf(v[2 * p + 1].x) << 16);
            unsigned int d1 = (unsigned int)f2bf(v[2 * p].y) | ((unsigned int)f2bf(v[2 * p + 1].y) << 16);
            unsigned int d2 = (unsigned int)f2bf(v[2 * p].z) | ((unsigned int)f2bf(v[2 * p + 1].z) << 16);
            unsigned int d3 = (unsigned int)f2bf(v[2 * p].w) | ((unsigned int)f2bf(v[2 * p + 1].w) << 16);
            *(uint4*)&l32[(size_t)(kg * 4 + p) * 260 + nl * 4] = make_uint4(d0, d1, d2, d3);
        }
        __syncthreads();
#pragma unroll
        for (int i = 0; i < 4; ++i) {
            int cid = i * 1024 + tid;
            int nloc = cid >> 4, kc = cid & 15;
            int n = nb + nloc;
            if (n < nmax) {
                unsigned int u0 = l32[(size_t)(kc * 4 + 0) * 260 + nloc];
                unsigned int u1 = l32[(size_t)(kc * 4 + 1) * 260 + nloc];
                unsigned int u2 = l32[(size_t)(kc * 4 + 2) * 260 + nloc];
                unsigned int u3 = l32[(size_t)(kc * 4 + 3) * 260 + nloc];
                *(uint4*)&dst[(size_t)n * ldd + kb + kc * 8] = make_uint4(u0, u1, u2, u3);
            }
        }
    }
}

// ---------- K2c: decoder attention, all (t,row) in parallel ----------
__global__ __launch_bounds__(256) void dec_attn(const float* __restrict__ ct_all,
                                                const float* __restrict__ sdw, const float* __restrict__ sdb,
                                                const float* __restrict__ vatt,
                                                const float* __restrict__ henc,
                                                const float* __restrict__ hsf, const float* __restrict__ hsb,
                                                unsigned short* __restrict__ comb16) {
    int per = (int)gridDim.x >> 3;                    // 124
    int f = ((int)blockIdx.x & 7) * per + ((int)blockIdx.x >> 3);
    int row = f / 31, t = f - row * 31;
    int tid = threadIdx.x;
    __shared__ float c_l[256];
    __shared__ float catt[128];
    __shared__ float attn[256];
    __shared__ float red[256];
    __shared__ float vat[128];
    __shared__ float part[256];
    c_l[tid] = ct_all[(size_t)(t * 32 + row) * 256 + tid];
    if (tid < 128) vat[tid] = vatt[tid];
    __syncthreads();
    {
        int col = tid & 127, k0 = (tid >> 7) * 128;
        float aa = 0.0f;
#pragma unroll 4
        for (int k = 0; k < 128; ++k) aa += c_l[k0 + k] * sdw[(size_t)(k0 + k) * 128 + col];
        part[tid] = aa;
    }
    __syncthreads();
    if (tid < 128) catt[tid] = part[tid] + part[tid + 128] + sdb[tid];
    __syncthreads();
    {
        const float4* hp = (const float4*)&henc[(size_t)(row * 256 + tid) * 128];
        float aa = 0.0f;
#pragma unroll 4
        for (int e4 = 0; e4 < 32; ++e4) {
            float4 h4 = hp[e4];
            int e = 4 * e4;
            aa += tanh_(h4.x + catt[e + 0]) * vat[e + 0];
            aa += tanh_(h4.y + catt[e + 1]) * vat[e + 1];
            aa += tanh_(h4.z + catt[e + 2]) * vat[e + 2];
            aa += tanh_(h4.w + catt[e + 3]) * vat[e + 3];
        }
        attn[tid] = aa;
    }
    __syncthreads();
    red[tid] = attn[tid];
    __syncthreads();
    for (int off = 128; off; off >>= 1) {
        if (tid < off) red[tid] = fmaxf(red[tid], red[tid + off]);
        __syncthreads();
    }
    float mx = red[0];
    __syncthreads();
    float ex = __expf(attn[tid] - mx);
    red[tid] = ex;
    __syncthreads();
    for (int off = 128; off; off >>= 1) {
        if (tid < off) red[tid] += red[tid + off];
        __syncthreads();
    }
    float inv = 1.0f / red[0];
    __syncthreads();
    attn[tid] = ex * inv;
    __syncthreads();
    {
        float cx0 = 0.0f, cx1 = 0.0f;
#pragma unroll 4
        for (int s = 0; s < 256; ++s) {
            float aw = attn[s];
            cx0 += aw * hsf[(size_t)(s * 32 + row) * 256 + tid];
            cx1 += aw * hsb[(size_t)(s * 32 + row) * 256 + tid];
        }
        size_t base = (size_t)(t * 32 + row) * 768;
        comb16[base + tid] = f2bf(cx0);
        comb16[base + 256 + tid] = f2bf(cx1);
    }
}

// ---------- K3: henc_proj = enc @ henc_w + henc_b ----------
__global__ __launch_bounds__(256) void henc_kernel(const float* __restrict__ hsf, const float* __restrict__ hsb,
                                                   const float* __restrict__ hw, const float* __restrict__ hb,
                                                   float* __restrict__ henc) {
    __shared__ float Al[32][256];
    int r0 = blockIdx.x * 32;
    int tid = threadIdx.x;
    int rg = tid >> 5;
    int c = (tid & 31) * 4;
    float4 acc[4];
#pragma unroll
    for (int r = 0; r < 4; ++r) acc[r] = make_float4(0.f, 0.f, 0.f, 0.f);
    for (int kc = 0; kc < 2; ++kc) {
        const float* src_arr = kc ? hsb : hsf;
        {
            int ri = tid >> 3, cc = (tid & 7) * 32;
            int r = r0 + ri; int b = r >> 8, s = r & 255;
            const float4* sp = (const float4*)&src_arr[(size_t)(s * 32 + b) * 256 + cc];
            float4* dp = (float4*)&Al[ri][cc];
#pragma unroll
            for (int i = 0; i < 8; ++i) dp[i] = sp[i];
        }
        __syncthreads();
        for (int k = 0; k < 256; k += 4) {
            int kg = kc * 256 + k;
            float4 w0 = *(const float4*)&hw[(kg + 0) * 128 + c];
            float4 w1 = *(const float4*)&hw[(kg + 1) * 128 + c];
            float4 w2 = *(const float4*)&hw[(kg + 2) * 128 + c];
            float4 w3 = *(const float4*)&hw[(kg + 3) * 128 + c];
#pragma unroll
            for (int r = 0; r < 4; ++r) {
                float4 a = *(const float4*)&Al[rg * 4 + r][k];
                acc[r].x += a.x * w0.x + a.y * w1.x + a.z * w2.x + a.w * w3.x;
                acc[r].y += a.x * w0.y + a.y * w1.y + a.z * w2.y + a.w * w3.y;
                acc[r].z += a.x * w0.z + a.y * w1.z + a.z * w2.z + a.w * w3.z;
                acc[r].w += a.x * w0.w + a.y * w1.w + a.z * w2.w + a.w * w3.w;
            }
        }
        __syncthreads();
    }
    float4 b4 = *(const float4*)&hb[c];
#pragma unroll
    for (int r = 0; r < 4; ++r) {
        int row = r0 + rg * 4 + r;
        float4 v = make_float4(acc[r].x + b4.x, acc[r].y + b4.y, acc[r].z + b4.z, acc[r].w + b4.w);
        *(float4*)&henc[(size_t)row * 128 + c] = v;
    }
}

// ---------- K5: bf16 MFMA GEMM, both operands pre-packed bf16, m97 structure ----------
template <int MODE>
__global__ __launch_bounds__(256, 4) void gemm_bt(const unsigned short* __restrict__ A, int lda, int K,
                                                  const unsigned short* __restrict__ Bt, int ldb, int ncols,
                                                  const float* __restrict__ bias,
                                                  unsigned short* __restrict__ outC,
                                                  float* __restrict__ Pmax, float* __restrict__ Psum, int npart,
                                                  const int* __restrict__ targ, float* __restrict__ tlog) {
    __shared__ unsigned int AL[128 * 16];   // [row][16 dw], chunk c stored at c^((row>>1)&3)
    __shared__ unsigned int BL[128 * 16];   // [n][16 dw], same swizzle
    __shared__ int tgt_l[128];
    int per = (int)gridDim.x >> 3;
    int f = ((int)blockIdx.x & 7) * per + ((int)blockIdx.x >> 3);
    int ct = f >> 3, rt = f & 7;
    int tid = threadIdx.x;
    int lane = tid & 63, w = tid >> 6;
    int wr = w >> 1, wc = w & 1;
    if (MODE == 1 && tid < 128) {
        int row = rt * 128 + tid;
        int tt = row >> 5, bb = row & 31;
        tgt_l[tid] = (tt < 31) ? targ[bb * 32 + tt + 1] : -1;
    }
    f32x4 acc[4][4];
#pragma unroll
    for (int i = 0; i < 4; ++i)
#pragma unroll
        for (int j = 0; j < 4; ++j) acc[i][j] = (f32x4){0.f, 0.f, 0.f, 0.f};

    int P0 = tid,       r0 = P0 >> 2, c0 = (P0 & 3) ^ ((r0 >> 1) & 3);
    int P1 = 256 + tid, r1 = P1 >> 2, c1 = (P1 & 3) ^ ((r1 >> 1) & 3);
    const unsigned short* ag0 = A + (size_t)(rt * 128 + r0) * lda + c0 * 8;
    const unsigned short* ag1 = A + (size_t)(rt * 128 + r1) * lda + c1 * 8;
    const unsigned short* bg0 = Bt + (size_t)(ct * 128 + r0) * ldb + c0 * 8;
    const unsigned short* bg1 = Bt + (size_t)(ct * 128 + r1) * ldb + c1 * 8;
    unsigned int* adst0 = &AL[(size_t)(w * 64) * 4];          // wave-uniform bases
    unsigned int* adst1 = &AL[(size_t)(256 + w * 64) * 4];
    unsigned int* bdst0 = &BL[(size_t)(w * 64) * 4];
    unsigned int* bdst1 = &BL[(size_t)(256 + w * 64) * 4];

    int iters = K / 32;
    for (int it = 0; it < iters; ++it) {
        size_t k0 = (size_t)it * 32;
        __builtin_amdgcn_global_load_lds((GLDg*)(ag0 + k0), (GLDl*)adst0, 16, 0, 0);
        __builtin_amdgcn_global_load_lds((GLDg*)(ag1 + k0), (GLDl*)adst1, 16, 0, 0);
        __builtin_amdgcn_global_load_lds((GLDg*)(bg0 + k0), (GLDl*)bdst0, 16, 0, 0);
        __builtin_amdgcn_global_load_lds((GLDg*)(bg1 + k0), (GLDl*)bdst1, 16, 0, 0);
        __syncthreads();
        bf16x8 af[4];
#pragma unroll
        for (int i = 0; i < 4; ++i) {
            int r = wr * 64 + i * 16 + (lane & 15);
            int pos = (lane >> 4) ^ ((r >> 1) & 3);
            af[i] = *(const bf16x8*)&AL[r * 16 + pos * 4];
        }
#pragma unroll
        for (int j = 0; j < 4; ++j) {
            int n = wc * 64 + j * 16 + (lane & 15);
            int pos = (lane >> 4) ^ ((n >> 1) & 3);
            bf16x8 bfr = *(const bf16x8*)&BL[n * 16 + pos * 4];
#pragma unroll
            for (int i = 0; i < 4; ++i)
                acc[i][j] = __builtin_amdgcn_mfma_f32_16x16x32_bf16(af[i], bfr, acc[i][j], 0, 0, 0);
        }
        __syncthreads();
    }
    float bv[4]; bool vok[4];
#pragma unroll
    for (int j = 0; j < 4; ++j) {
        int col = ct * 128 + wc * 64 + j * 16 + (lane & 15);
        vok[j] = (col < ncols);
        bv[j] = vok[j] ? bias[col] : 0.0f;
    }
    if (MODE == 0) {
#pragma unroll
        for (int i = 0; i < 4; ++i)
#pragma unroll
            for (int reg = 0; reg < 4; ++reg) {
                int row = rt * 128 + wr * 64 + i * 16 + (lane >> 4) * 4 + reg;
#pragma unroll
                for (int j = 0; j < 4; ++j) {
                    int col = ct * 128 + wc * 64 + j * 16 + (lane & 15);
                    outC[(size_t)row * 4096 + col] = f2bf(acc[i][j][reg] + bv[j]);
                }
            }
    } else {
#pragma unroll
        for (int i = 0; i < 4; ++i)
#pragma unroll
            for (int reg = 0; reg < 4; ++reg) {
                int rowl = wr * 64 + i * 16 + (lane >> 4) * 4 + reg;
                int row = rt * 128 + rowl;
                int ntgt = tgt_l[rowl];
                float v[4];
                float m = -1e30f;
#pragma unroll
                for (int j = 0; j < 4; ++j) {
                    v[j] = vok[j] ? (acc[i][j][reg] + bv[j]) : -1e30f;
                    m = fmaxf(m, v[j]);
                }
#pragma unroll
                for (int j = 0; j < 4; ++j) {
                    int col = ct * 128 + wc * 64 + j * 16 + (lane & 15);
                    if (col == ntgt) tlog[row] = v[j];
                }
                m = fmaxf(m, __shfl_xor(m, 1));
                m = fmaxf(m, __shfl_xor(m, 2));
                m = fmaxf(m, __shfl_xor(m, 4));
                m = fmaxf(m, __shfl_xor(m, 8));
                float s = 0.0f;
#pragma unroll
                for (int j = 0; j < 4; ++j) s += __expf(v[j] - m);
                s += __shfl_xor(s, 1);
                s += __shfl_xor(s, 2);
                s += __shfl_xor(s, 4);
                s += __shfl_xor(s, 8);
                if ((lane & 15) == 0) {
                    Pmax[(size_t)row * npart + ct * 2 + wc] = m;
                    Psum[(size_t)row * npart + ct * 2 + wc] = s;
                }
            }
    }
}

// ---------- K5-fallback: fp32-B GEMM (used when workspace too small for lvwT) ----------
__global__ __launch_bounds__(256, 3) void gemm_big1(const unsigned short* __restrict__ A, int lda, int K,
                                                    const float* __restrict__ Bm, int Nstride,
                                                    const float* __restrict__ bias,
                                                    float* __restrict__ Pmax, float* __restrict__ Psum, int npart,
                                                    const int* __restrict__ targ, float* __restrict__ tlog) {
    __shared__ unsigned int AL[128 * 16];
    __shared__ unsigned int BL[128 * 16];
    __shared__ int tgt_l[128];
    int per = (int)gridDim.x >> 3;
    int f = ((int)blockIdx.x & 7) * per + ((int)blockIdx.x >> 3);
    int ct = f >> 3, rt = f & 7;
    int tid = threadIdx.x;
    int lane = tid & 63, w = tid >> 6;
    int wr = w >> 1, wc = w & 1;
    if (tid < 128) {
        int row = rt * 128 + tid;
        int tt = row >> 5, bb = row & 31;
        tgt_l[tid] = (tt < 31) ? targ[bb * 32 + tt + 1] : -1;
    }
    f32x4 acc[4][4];
#pragma unroll
    for (int i = 0; i < 4; ++i)
#pragma unroll
        for (int j = 0; j < 4; ++j) acc[i][j] = (f32x4){0.f, 0.f, 0.f, 0.f};
    int P0 = tid,       r0 = P0 >> 2, c0 = (P0 & 3) ^ ((r0 >> 1) & 3);
    int P1 = 256 + tid, r1 = P1 >> 2, c1 = (P1 & 3) ^ ((r1 >> 1) & 3);
    const unsigned short* ag0 = A + (size_t)(rt * 128 + r0) * lda + c0 * 8;
    const unsigned short* ag1 = A + (size_t)(rt * 128 + r1) * lda + c1 * 8;
    unsigned int* ldst0 = &AL[(size_t)(w * 64) * 4];
    unsigned int* ldst1 = &AL[(size_t)(256 + w * 64) * 4];
    int bn = tid & 127, bkh = tid >> 7;
    int coln = ct * 128 + bn;
    bool colok = (coln < Nstride);
    const float* bp = Bm + (size_t)(bkh * 16) * Nstride + (colok ? coln : 0);
    int bs = (bn >> 1) & 3;
    unsigned int* bw0 = &BL[bn * 16 + (((bkh * 2) ^ bs) * 4)];
    unsigned int* bw1 = &BL[bn * 16 + (((bkh * 2 + 1) ^ bs) * 4)];
    int iters = K / 32;
    for (int it = 0; it < iters; ++it) {
        size_t k0 = (size_t)it * 32;
        __builtin_amdgcn_global_load_lds((GLDg*)(ag0 + k0), (GLDl*)ldst0, 16, 0, 0);
        __builtin_amdgcn_global_load_lds((GLDg*)(ag1 + k0), (GLDl*)ldst1, 16, 0, 0);
        {
            const float* bq = bp + k0 * Nstride;
            unsigned int dw[8];
#pragma unroll
            for (int i = 0; i < 8; ++i) {
                float f0 = colok ? bq[(size_t)(2 * i) * Nstride] : 0.0f;
                float f1 = colok ? bq[(size_t)(2 * i + 1) * Nstride] : 0.0f;
                dw[i] = (unsigned int)f2bf(f0) | ((unsigned int)f2bf(f1) << 16);
            }
            *(uint4*)bw0 = make_uint4(dw[0], dw[1], dw[2], dw[3]);
            *(uint4*)bw1 = make_uint4(dw[4], dw[5], dw[6], dw[7]);
        }
        __syncthreads();
        bf16x8 af[4];
#pragma unroll
        for (int i = 0; i < 4; ++i) {
            int r = wr * 64 + i * 16 + (lane & 15);
            int pos = (lane >> 4) ^ ((r >> 1) & 3);
            af[i] = *(const bf16x8*)&AL[r * 16 + pos * 4];
        }
#pragma unroll
        for (int j = 0; j < 4; ++j) {
            int n = wc * 64 + j * 16 + (lane & 15);
            int pos = (lane >> 4) ^ ((n >> 1) & 3);
            bf16x8 bfr = *(const bf16x8*)&BL[n * 16 + pos * 4];
#pragma unroll
            for (int i = 0; i < 4; ++i)
                acc[i][j] = __builtin_amdgcn_mfma_f32_16x16x32_bf16(af[i], bfr, acc[i][j], 0, 0, 0);
        }
        __syncthreads();
    }
    float bv[4]; bool vok[4];
#pragma unroll
    for (int j = 0; j < 4; ++j) {
        int col = ct * 128 + wc * 64 + j * 16 + (lane & 15);
        vok[j] = (col < Nstride);
        bv[j] = vok[j] ? bias[col] : 0.0f;
    }
#pragma unroll
    for (int i = 0; i < 4; ++i)
#pragma unroll
        for (int reg = 0; reg < 4; ++reg) {
            int rowl = wr * 64 + i * 16 + (lane >> 4) * 4 + reg;
            int row = rt * 128 + rowl;
            int ntgt = tgt_l[rowl];
            float v[4];
            float m = -1e30f;
#pragma unroll
            for (int j = 0; j < 4; ++j) {
                v[j] = vok[j] ? (acc[i][j][reg] + bv[j]) : -1e30f;
                m = fmaxf(m, v[j]);
            }
#pragma unroll
            for (int j = 0; j < 4; ++j) {
                int col = ct * 128 + wc * 64 + j * 16 + (lane & 15);
                if (col == ntgt) tlog[row] = v[j];
            }
            m = fmaxf(m, __shfl_xor(m, 1));
            m = fmaxf(m, __shfl_xor(m, 2));
            m = fmaxf(m, __shfl_xor(m, 4));
            m = fmaxf(m, __shfl_xor(m, 8));
            float s = 0.0f;
#pragma unroll
            for (int j = 0; j < 4; ++j) s += __expf(v[j] - m);
            s += __shfl_xor(s, 1);
            s += __shfl_xor(s, 2);
            s += __shfl_xor(s, 4);
            s += __shfl_xor(s, 8);
            if ((lane & 15) == 0) {
                Pmax[(size_t)row * npart + ct * 2 + wc] = m;
                Psum[(size_t)row * npart + ct * 2 + wc] = s;
            }
        }
}

// ---------- K5d: per-row logsumexp + nll ----------
__global__ __launch_bounds__(256) void lse_nll(const float* __restrict__ Pmax, const float* __restrict__ Psum,
                                               const float* __restrict__ tlog, const int* __restrict__ targ,
                                               float* __restrict__ nll) {
    int row = blockIdx.x;
    int t = row >> 5, b = row & 31;
    int tid = threadIdx.x;
    __shared__ float rm[256];
    __shared__ float rs[256];
    float m = -1e30f;
    for (int i = tid; i < NPART; i += 256) m = fmaxf(m, Pmax[(size_t)row * NPART + i]);
    rm[tid] = m;
    __syncthreads();
    for (int off = 128; off; off >>= 1) {
        if (tid < off) rm[tid] = fmaxf(rm[tid], rm[tid + off]);
        __syncthreads();
    }
    m = rm[0];
    float s = 0.0f;
    for (int i = tid; i < NPART; i += 256)
        s += Psum[(size_t)row * NPART + i] * __expf(Pmax[(size_t)row * NPART + i] - m);
    rs[tid] = s;
    __syncthreads();
    for (int off = 128; off; off >>= 1) {
        if (tid < off) rs[tid] += rs[tid + off];
        __syncthreads();
    }
    if (tid == 0) {
        float lse = m + logf(rs[0]);
        float out = 0.0f;
        if (t < 31) {
            int tg = targ[b * 32 + t + 1];
            if (tg != 0) out = lse - tlog[row];
        }
        nll[row] = out;
    }
}

// ---------- K6: final reduce ----------
__global__ __launch_bounds__(256) void finloss(const float* __restrict__ nll, float* __restrict__ out) {
    __shared__ float red[256];
    int tid = threadIdx.x;
    float a = 0.0f;
    for (int i = tid; i < 1024; i += 256) a += nll[i];
    red[tid] = a;
    __syncthreads();
    for (int off = 128; off; off >>= 1) {
        if (tid < off) red[tid] += red[tid + off];
        __syncthreads();
    }
    if (tid == 0) out[0] = red[0] * (1.0f / 1024.0f);
}

extern "C" void kernel_launch(void* const* d_in, const int* in_sizes, int n_in,
                              void* d_out, int out_size, void* d_ws, size_t ws_size,
                              hipStream_t stream) {
    const int* inp = (const int*)d_in[0];
    const int* targ = (const int*)d_in[1];
    const float* emb = (const float*)d_in[2];
    const float* ekf = (const float*)d_in[3];
    const float* erf = (const float*)d_in[4];
    const float* ebf = (const float*)d_in[5];
    const float* ekb = (const float*)d_in[6];
    const float* erb = (const float*)d_in[7];
    const float* ebb = (const float*)d_in[8];
    const float* dk  = (const float*)d_in[9];
    const float* dr  = (const float*)d_in[10];
    const float* db  = (const float*)d_in[11];
    const float* hw  = (const float*)d_in[12];
    const float* hb  = (const float*)d_in[13];
    const float* sdw = (const float*)d_in[14];
    const float* sdb = (const float*)d_in[15];
    const float* vat = (const float*)d_in[16];
    const float* lfw = (const float*)d_in[17];
    const float* lfb = (const float*)d_in[18];
    const float* lvw = (const float*)d_in[19];
    const float* lvb = (const float*)d_in[20];

    float* ws = (float*)d_ws;
    float* xkf = ws + OFF_XKF;
    float* xkb = ws + OFF_XKB;
    float* xkd = ws + OFF_XKD;
    float* hsf = ws + OFF_HSF;
    float* hsb = ws + OFF_HSB;
    float* henc = ws + OFF_HENC;
    unsigned int* erpf = (unsigned int*)(ws + OFF_ERPF);
    unsigned int* erpb = (unsigned int*)(ws + OFF_ERPB);
    unsigned int* drp  = (unsigned int*)(ws + OFF_DRP);
    unsigned short* comb16 = (unsigned short*)(ws + OFF_COMB);
    unsigned short* fb16   = (unsigned short*)(ws + OFF_FB16);
    unsigned short* lfwT   = (unsigned short*)(ws + OFF_LFWT);
    unsigned short* lvwT   = (unsigned short*)(ws + OFF_LVWT);
    float* pmax = ws + OFF_PMAX;
    float* psum = ws + OFF_PSUM;
    float* tlog = ws + OFF_TLOG;
    float* nllb = ws + OFF_NLL;
    float* ct_all = ws + OFF_CT;

    bool big = (ws_size >= WS_NEED_BYTES);

    static bool attr_set = false;
    if (!attr_set) {
        hipFuncSetAttribute((const void*)lstm_cvt_fused,
                            hipFuncAttributeMaxDynamicSharedMemorySize, (int)ENC_LDS_BYTES);
        attr_set = true;
    }

    hipLaunchKernelGGL(pack_half_k, dim3(1536), dim3(256), 0, stream, erf, erb, dr, erpf, erpb, drp);
    hipLaunchKernelGGL(xgate_kernel, dim3(128, 8), dim3(256), 0, stream, emb, inp, 0, ekf, ebf, xkf);
    hipLaunchKernelGGL(xgate_kernel, dim3(128, 8), dim3(256), 0, stream, emb, inp, 0, ekb, ebb, xkb);
    hipLaunchKernelGGL(xgate_kernel, dim3(16, 8), dim3(256), 0, stream, emb, targ, 1, dk, db, xkd);
    // fused: enc_lstm (blk 0-63) + dec_lstm (blk 64-95) + lfw cvt (96-191) + lvw cvt (192+)
    {
        int nblk = big ? (192 + 6272) : 192;
        hipLaunchKernelGGL(lstm_cvt_fused, dim3(nblk), dim3(1024), ENC_LDS_BYTES, stream,
                           xkf, xkb, erpf, erpb, hsf, hsb,
                           xkd, drp, ct_all, comb16,
                           lfw, lfwT, lvw, lvwT);
    }
    hipLaunchKernelGGL(henc_kernel, dim3(256), dim3(256), 0, stream, hsf, hsb, hw, hb, henc);
    hipLaunchKernelGGL(dec_attn, dim3(992), dim3(256), 0, stream,
                       ct_all, sdw, sdb, vat, henc, hsf, hsb, comb16);
    hipLaunchKernelGGL((gemm_bt<0>), dim3(256), dim3(256), 0, stream,
                       comb16, 768, 768, lfwT, 768, 4096, lfb, fb16,
                       (float*)nullptr, (float*)nullptr, 0, (const int*)nullptr, (float*)nullptr);
    if (big)
        hipLaunchKernelGGL((gemm_bt<1>), dim3(3128), dim3(256), 0, stream,
                           fb16, 4096, 4096, lvwT, 4096, 50000, lvb, (unsigned short*)nullptr,
                           pmax, psum, NPART, targ, tlog);
    else
        hipLaunchKernelGGL(gemm_big1, dim3(3128), dim3(256), 0, stream,
                           fb16, 4096, 4096, lvw, 50000, lvb, pmax, psum, NPART, targ, tlog);
    hipLaunchKernelGGL(lse_nll, dim3(1024), dim3(256), 0, stream, pmax, psum, tlog, targ, nllb);
    hipLaunchKernelGGL(finloss, dim3(1), dim3(256), 0, stream, nllb, (float*)d_out);
}

// Round 11
// 2150.960 us; speedup vs baseline: 1.4703x; 1.4703x over previous
//
#include <hip/hip_runtime.h>

#define DEV __device__ __forceinline__

typedef __attribute__((ext_vector_type(8))) short bf16x8;
typedef __attribute__((ext_vector_type(4))) float f32x4;
typedef __attribute__((ext_vector_type(2))) _Float16 h2_t;

typedef __attribute__((address_space(1))) const void GLDg;
typedef __attribute__((address_space(3))) void GLDl;

// ---------- constants ----------
static const int V = 50000, E = 128, H = 256, B = 32, S = 256, T = 32, FF = 4096;
static const int NCT = 391;           // ceil(50000/128)
static const int NPART = 782;         // 391 col tiles x 2 wave-cols
// workspace offsets (in floats)
static const size_t OFF_XKF  = 0;                     // S*B*4H = 8388608
static const size_t OFF_XKB  = 8388608;               // 8388608
static const size_t OFF_XKD  = 16777216;              // T*B*4H = 1048576
static const size_t OFF_HSF  = 17825792;              // S*B*H = 2097152
static const size_t OFF_HSB  = 19922944;              // 2097152
static const size_t OFF_HENC = 22020096;              // B*S*E = 1048576
static const size_t OFF_ERPF = 23068672;              // 131072 (uint)
static const size_t OFF_ERPB = 23199744;
static const size_t OFF_DRP  = 23330816;
static const size_t OFF_COMB = 23461888;              // 1024*768 ushort = 393216 floats
static const size_t OFF_FB16 = 23855104;              // 1024*4096 ushort = 2097152 floats
static const size_t OFF_LFWT = 25952256;              // 4096*768 ushort = 1572864 floats
static const size_t OFF_LVWT = 27525120;              // 50048*4096 ushort = 102498304 floats
static const size_t LVWT_FLOATS = 102498304;
static const size_t WS_NEED_BYTES = (OFF_LVWT + LVWT_FLOATS) * 4;   // ~520 MB
// scratch in the xkf region (dead after enc_lstm / before gemm respectively)
static const size_t OFF_PMAX = 0;                     // 1024*782 = 800768
static const size_t OFF_PSUM = 800768;
static const size_t OFF_TLOG = 1601536;
static const size_t OFF_NLL  = 1602560;
static const size_t OFF_CT   = 1603584;               // 31*32*256 = 253952 floats

// dynamic LDS for the fused LSTM+cvt kernel: 2*64KB weights + 512B h2 + 4KB zg
static const size_t ENC_LDS_BYTES = 65536 * 2 + 512 + 4096;   // 136192

// ---------- helpers ----------
DEV float sigf(float x) { return 1.0f / (1.0f + __expf(-x)); }
DEV float tanh_(float x) {
    x = fminf(fmaxf(x, -20.0f), 20.0f);
    float e = __expf(2.0f * x);
    return (e - 1.0f) / (e + 1.0f);
}
DEV unsigned short f2bf(float f) {
    unsigned int u = __builtin_bit_cast(unsigned int, f);
    u += 0x7FFFu + ((u >> 16) & 1u);
    return (unsigned short)(u >> 16);
}
DEV float bf2f(unsigned short s) {
    unsigned int u = ((unsigned int)s) << 16;
    return __builtin_bit_cast(float, u);
}
DEV float dot2u(unsigned int a, unsigned int b, float c) {
#if __has_builtin(__builtin_amdgcn_fdot2)
    return __builtin_amdgcn_fdot2(__builtin_bit_cast(h2_t, a), __builtin_bit_cast(h2_t, b), c, false);
#else
    h2_t x = __builtin_bit_cast(h2_t, a), y = __builtin_bit_cast(h2_t, b);
    return c + (float)x[0] * (float)y[0] + (float)x[1] * (float)y[1];
#endif
}

// ---------- K0: pack recurrent weights (H x 4H fp32) -> half2 dwords, COL-major [c][k2] ----------
__global__ void pack_half_k(const float* __restrict__ erf, const float* __restrict__ erb,
                            const float* __restrict__ dr,
                            unsigned int* __restrict__ pf, unsigned int* __restrict__ pb,
                            unsigned int* __restrict__ pd) {
    int id = blockIdx.x * 256 + threadIdx.x;          // 3*131072 total
    int which = id >> 17;
    int rem = id & 131071;
    const float* s = (which == 0) ? erf : (which == 1) ? erb : dr;
    unsigned int* o = (which == 0) ? pf : (which == 1) ? pb : pd;
    int cc = rem >> 7, k2 = rem & 127;                // o[cc*128+k2]
    float v0 = s[(2 * k2) * 1024 + cc];
    float v1 = s[(2 * k2 + 1) * 1024 + cc];
    h2_t h; h[0] = (_Float16)v0; h[1] = (_Float16)v1;
    o[rem] = __builtin_bit_cast(unsigned int, h);
}

// ---------- K1: gathered x@W + b  (M x 128)@(128 x 1024) ----------
__global__ __launch_bounds__(256) void xgate_kernel(const float* __restrict__ emb,
                                                    const int* __restrict__ tok_src, int dec_mode,
                                                    const float* __restrict__ wt,
                                                    const float* __restrict__ bias,
                                                    float* __restrict__ out) {
    __shared__ float Al[64][128];
    __shared__ int tk[64];
    int r0 = blockIdx.x * 64, c0b = blockIdx.y * 128;
    int tid = threadIdx.x;
    if (tid < 64) {
        int r = r0 + tid; int hi = r >> 5, b = r & 31; int token;
        if (dec_mode) token = (hi == 0) ? 2 : tok_src[b * 32 + hi];
        else          token = tok_src[b * 256 + hi];
        tk[tid] = token;
    }
    __syncthreads();
    {
        int ri = tid >> 2, cc = (tid & 3) * 32;
        const float4* src = (const float4*)&emb[(size_t)tk[ri] * 128 + cc];
        float4* dst = (float4*)&Al[ri][cc];
#pragma unroll
        for (int i = 0; i < 8; ++i) dst[i] = src[i];
    }
    __syncthreads();
    int rg = tid >> 5;
    int c = c0b + (tid & 31) * 4;
    float4 acc[8];
#pragma unroll
    for (int r = 0; r < 8; ++r) acc[r] = make_float4(0.f, 0.f, 0.f, 0.f);
    for (int k = 0; k < 128; k += 4) {
        float4 w0 = *(const float4*)&wt[(k + 0) * 1024 + c];
        float4 w1 = *(const float4*)&wt[(k + 1) * 1024 + c];
        float4 w2 = *(const float4*)&wt[(k + 2) * 1024 + c];
        float4 w3 = *(const float4*)&wt[(k + 3) * 1024 + c];
#pragma unroll
        for (int r = 0; r < 8; ++r) {
            float4 a = *(const float4*)&Al[rg * 8 + r][k];
            acc[r].x += a.x * w0.x + a.y * w1.x + a.z * w2.x + a.w * w3.x;
            acc[r].y += a.x * w0.y + a.y * w1.y + a.z * w2.y + a.w * w3.y;
            acc[r].z += a.x * w0.z + a.y * w1.z + a.z * w2.z + a.w * w3.z;
            acc[r].w += a.x * w0.w + a.y * w1.w + a.z * w2.w + a.w * w3.w;
        }
    }
    float4 b4 = *(const float4*)&bias[c];
#pragma unroll
    for (int r = 0; r < 8; ++r) {
        int row = r0 + rg * 8 + r;
        float4 v = make_float4(acc[r].x + b4.x, acc[r].y + b4.y, acc[r].z + b4.z, acc[r].w + b4.w);
        *(float4*)&out[(size_t)row * 1024 + c] = v;
    }
}

// ---------- K2: FUSED enc_lstm (64 blk) + dec_lstm (32 blk) + weight cvt (rest) ----------
// 512 threads. LSTM: 2 cols/thread; weights split to FIT the 128-VGPR grant:
// quads 0-11 in regs (96 dwords, no spill), 12-19 in LDS (128KB), 20-31 streamed
// from L2 (384B/thread/step, contiguous). cvt: 256n x 64k float4 tiles (R9-proven).
extern __shared__ unsigned char dyn_lds[];
__global__ __launch_bounds__(512)
__attribute__((amdgpu_waves_per_eu(2, 2)))
void lstm_cvt_fused(
        const float* __restrict__ xkf, const float* __restrict__ xkb,
        const unsigned int* __restrict__ erpf, const unsigned int* __restrict__ erpb,
        float* __restrict__ hsf, float* __restrict__ hsb,
        const float* __restrict__ xkd, const unsigned int* __restrict__ drp,
        float* __restrict__ ct_all, unsigned short* __restrict__ comb16,
        const float* __restrict__ lfw, unsigned short* __restrict__ lfwT,
        const float* __restrict__ lvw, unsigned short* __restrict__ lvwT) {
    int bid = blockIdx.x;
    int tid = threadIdx.x;
    if (bid < 96) {
        // ----- LSTM recurrence (enc: bid<64, dec: 64..95) -----
        int is_dec = (bid >= 64);
        int dir = is_dec ? 0 : (bid >> 5);
        int row = is_dec ? (bid - 64) : (bid & 31);
        const float* xk = is_dec ? xkd : (dir ? xkb : xkf);
        const unsigned int* erp = is_dec ? drp : (dir ? erpb : erpf);
        float* hs = dir ? hsb : hsf;
        int nsteps = is_dec ? 31 : 256;
        int ca = 2 * tid;
        uint4* wlA = (uint4*)dyn_lds;                      // [8][512]
        uint4* wlB = (uint4*)(dyn_lds + 65536);            // [8][512]
        unsigned int* h2 = (unsigned int*)(dyn_lds + 131072);
        float* zg = (float*)(dyn_lds + 131072 + 512);

        const uint4* pa = (const uint4*)&erp[(size_t)ca * 128];        // 32 uint4/col
        const uint4* pb = (const uint4*)&erp[(size_t)(ca + 1) * 128];
        uint4 wa[12], wb[12];
#pragma unroll
        for (int i = 0; i < 12; ++i) { wa[i] = pa[i]; wb[i] = pb[i]; }
        // pin weights into VGPRs (96 dwords: fits the 128-VGPR grant, no spill)
#pragma unroll
        for (int i = 0; i < 12; ++i) {
            asm volatile("" : "+v"(wa[i].x), "+v"(wa[i].y), "+v"(wa[i].z), "+v"(wa[i].w),
                             "+v"(wb[i].x), "+v"(wb[i].y), "+v"(wb[i].z), "+v"(wb[i].w));
        }
#pragma unroll
        for (int j = 0; j < 8; ++j) { wlA[j * 512 + tid] = pa[12 + j]; wlB[j * 512 + tid] = pb[12 + j]; }
        const uint4* sa = pa + 20;                         // streamed quads 20..31
        const uint4* sb = pb + 20;
        if (tid < 128) h2[tid] = 0u;
        float c_reg = 0.0f;
        __syncthreads();
        int s0 = (!is_dec && dir) ? (nsteps - 1) : 0;
        float2 xcur = *(const float2*)&xk[(size_t)(s0 * 32 + row) * 1024 + ca];
        for (int si = 0; si < nsteps; ++si) {
            int s = (!is_dec && dir) ? (nsteps - 1 - si) : si;
            float2 xnext = make_float2(0.f, 0.f);
            if (si + 1 < nsteps) {
                int sn = (!is_dec && dir) ? (nsteps - 2 - si) : (si + 1);
                xnext = *(const float2*)&xk[(size_t)(sn * 32 + row) * 1024 + ca];
            }
            float acc0 = xcur.x, acc1 = xcur.y;
            // regs: k2 quads 0..11  (h2[0..47])
#pragma unroll
            for (int i = 0; i < 12; ++i) {
                uint4 hv = *(const uint4*)&h2[4 * i];
                acc0 = dot2u(hv.x, wa[i].x, acc0);
                acc0 = dot2u(hv.y, wa[i].y, acc0);
                acc0 = dot2u(hv.z, wa[i].z, acc0);
                acc0 = dot2u(hv.w, wa[i].w, acc0);
                acc1 = dot2u(hv.x, wb[i].x, acc1);
                acc1 = dot2u(hv.y, wb[i].y, acc1);
                acc1 = dot2u(hv.z, wb[i].z, acc1);
                acc1 = dot2u(hv.w, wb[i].w, acc1);
            }
            // LDS: quads 12..19  (h2[48..79])
#pragma unroll
            for (int j = 0; j < 8; ++j) {
                uint4 hv = *(const uint4*)&h2[48 + 4 * j];
                uint4 qa = wlA[j * 512 + tid];
                uint4 qb = wlB[j * 512 + tid];
                acc0 = dot2u(hv.x, qa.x, acc0);
                acc0 = dot2u(hv.y, qa.y, acc0);
                acc0 = dot2u(hv.z, qa.z, acc0);
                acc0 = dot2u(hv.w, qa.w, acc0);
                acc1 = dot2u(hv.x, qb.x, acc1);
                acc1 = dot2u(hv.y, qb.y, acc1);
                acc1 = dot2u(hv.z, qb.z, acc1);
                acc1 = dot2u(hv.w, qb.w, acc1);
            }
            // L2 stream: quads 20..31  (h2[80..127])
#pragma unroll
            for (int m = 0; m < 12; ++m) {
                uint4 hv = *(const uint4*)&h2[80 + 4 * m];
                uint4 qa = sa[m];
                uint4 qb = sb[m];
                acc0 = dot2u(hv.x, qa.x, acc0);
                acc0 = dot2u(hv.y, qa.y, acc0);
                acc0 = dot2u(hv.z, qa.z, acc0);
                acc0 = dot2u(hv.w, qa.w, acc0);
                acc1 = dot2u(hv.x, qb.x, acc1);
                acc1 = dot2u(hv.y, qb.y, acc1);
                acc1 = dot2u(hv.z, qb.z, acc1);
                acc1 = dot2u(hv.w, qb.w, acc1);
            }
            *(float2*)&zg[ca] = make_float2(acc0, acc1);
            __syncthreads();
            if (tid < 256) {
                float ii = zg[tid], ff = zg[tid + 256], gg = zg[tid + 512], oo = zg[tid + 768];
                c_reg = sigf(ff) * c_reg + sigf(ii) * tanh_(gg);
                float h = sigf(oo) * tanh_(c_reg);
                ((_Float16*)h2)[tid] = (_Float16)h;
                if (is_dec) {
                    ct_all[(size_t)(s * 32 + row) * 256 + tid] = c_reg;
                    comb16[(size_t)(s * 32 + row) * 768 + 512 + tid] = f2bf(c_reg);
                } else {
                    hs[(size_t)(s * 32 + row) * 256 + tid] = h;
                }
            }
            __syncthreads();
            xcur = xnext;
        }
        if (is_dec) {       // zero pad rows 992..1023 of comb16
            size_t base = (size_t)(31 * 32 + row) * 768;
            for (int j = tid; j < 768; j += 512) comb16[base + j] = 0;
        }
    } else {
        // ----- weight convert+transpose, 256n x 64k tile per block, float4 loads -----
        const float* src; unsigned short* dst; int N, ldd, nb, kb, nmax;
        if (bid < 96 + 192) {
            int f2 = bid - 96;                    // lfw: 16 n-tiles x 12 k-tiles
            src = lfw; dst = lfwT; N = 4096; ldd = 768; nmax = 4096;
            nb = (f2 & 15) * 256; kb = (f2 >> 4) * 64;
        } else {
            int f3 = bid - 288;                   // lvw: 196 n-tiles x 64 k-tiles
            src = lvw; dst = lvwT; N = 50000; ldd = 4096; nmax = 50048;
            int nbi = f3 % 196, kbi = f3 / 196;
            nb = nbi * 256; kb = kbi * 64;
        }
        unsigned int* l32 = (unsigned int*)dyn_lds;        // [32 kpair][260 dw]
        int nl = tid & 63, kg = tid >> 6;                  // kg 0..7, each: 8 k-rows
        float4 v[8];
        if (nb + 256 <= N) {
            const float* sp = src + (size_t)(kb + kg * 8) * N + nb + nl * 4;
#pragma unroll
            for (int j = 0; j < 8; ++j) v[j] = *(const float4*)(sp + (size_t)j * N);
        } else {
#pragma unroll
            for (int j = 0; j < 8; ++j) {
                int n0 = nb + nl * 4;
                const float* rp = src + (size_t)(kb + kg * 8 + j) * N;
                v[j].x = (n0 + 0 < N) ? rp[n0 + 0] : 0.0f;
                v[j].y = (n0 + 1 < N) ? rp[n0 + 1] : 0.0f;
                v[j].z = (n0 + 2 < N) ? rp[n0 + 2] : 0.0f;
                v[j].w = (n0 + 3 < N) ? rp[n0 + 3] : 0.0f;
            }
        }
#pragma unroll
        for (int p = 0; p < 4; ++p) {           // k-pair (2p, 2p+1)
            unsigned int d0 = (unsigned int)f2bf(v[2 * p].x) | ((unsigned int)f2bf(v[2 * p + 1].x) << 16);
            unsigned int d1 = (unsigned int)f2bf(v[2 * p].y) | ((unsigned int)f2bf(v[2 * p + 1].y) << 16);
            unsigned int d2 = (unsigned int)f2bf(v[2 * p].z) | ((unsigned int)f2bf(v[2 * p + 1].z) << 16);
            unsigned int d3 = (unsigned int)f2bf(v[2 * p].w) | ((unsigned int)f2bf(v[2 * p + 1].w) << 16);
            *(uint4*)&l32[(size_t)(kg * 4 + p) * 260 + nl * 4] = make_uint4(d0, d1, d2, d3);
        }
        __syncthreads();
#pragma unroll
        for (int i = 0; i < 4; ++i) {
            int cid = i * 512 + tid;
            int nloc = cid >> 3, kc = cid & 7;
            int n = nb + nloc;
            if (n < nmax) {
                unsigned int u0 = l32[(size_t)(kc * 4 + 0) * 260 + nloc];
                unsigned int u1 = l32[(size_t)(kc * 4 + 1) * 260 + nloc];
                unsigned int u2 = l32[(size_t)(kc * 4 + 2) * 260 + nloc];
                unsigned int u3 = l32[(size_t)(kc * 4 + 3) * 260 + nloc];
                *(uint4*)&dst[(size_t)n * ldd + kb + kc * 8] = make_uint4(u0, u1, u2, u3);
            }
        }
    }
}

// ---------- K2c: decoder attention, all (t,row) in parallel ----------
__global__ __launch_bounds__(256) void dec_attn(const float* __restrict__ ct_all,
                                                const float* __restrict__ sdw, const float* __restrict__ sdb,
                                                const float* __restrict__ vatt,
                                                const float* __restrict__ henc,
                                                const float* __restrict__ hsf, const float* __restrict__ hsb,
                                                unsigned short* __restrict__ comb16) {
    int per = (int)gridDim.x >> 3;                    // 124
    int f = ((int)blockIdx.x & 7) * per + ((int)blockIdx.x >> 3);
    int row = f / 31, t = f - row * 31;
    int tid = threadIdx.x;
    __shared__ float c_l[256];
    __shared__ float catt[128];
    __shared__ float attn[256];
    __shared__ float red[256];
    __shared__ float vat[128];
    __shared__ float part[256];
    c_l[tid] = ct_all[(size_t)(t * 32 + row) * 256 + tid];
    if (tid < 128) vat[tid] = vatt[tid];
    __syncthreads();
    {
        int col = tid & 127, k0 = (tid >> 7) * 128;
        float aa = 0.0f;
#pragma unroll 4
        for (int k = 0; k < 128; ++k) aa += c_l[k0 + k] * sdw[(size_t)(k0 + k) * 128 + col];
        part[tid] = aa;
    }
    __syncthreads();
    if (tid < 128) catt[tid] = part[tid] + part[tid + 128] + sdb[tid];
    __syncthreads();
    {
        const float4* hp = (const float4*)&henc[(size_t)(row * 256 + tid) * 128];
        float aa = 0.0f;
#pragma unroll 4
        for (int e4 = 0; e4 < 32; ++e4) {
            float4 h4 = hp[e4];
            int e = 4 * e4;
            aa += tanh_(h4.x + catt[e + 0]) * vat[e + 0];
            aa += tanh_(h4.y + catt[e + 1]) * vat[e + 1];
            aa += tanh_(h4.z + catt[e + 2]) * vat[e + 2];
            aa += tanh_(h4.w + catt[e + 3]) * vat[e + 3];
        }
        attn[tid] = aa;
    }
    __syncthreads();
    red[tid] = attn[tid];
    __syncthreads();
    for (int off = 128; off; off >>= 1) {
        if (tid < off) red[tid] = fmaxf(red[tid], red[tid + off]);
        __syncthreads();
    }
    float mx = red[0];
    __syncthreads();
    float ex = __expf(attn[tid] - mx);
    red[tid] = ex;
    __syncthreads();
    for (int off = 128; off; off >>= 1) {
        if (tid < off) red[tid] += red[tid + off];
        __syncthreads();
    }
    float inv = 1.0f / red[0];
    __syncthreads();
    attn[tid] = ex * inv;
    __syncthreads();
    {
        float cx0 = 0.0f, cx1 = 0.0f;
#pragma unroll 4
        for (int s = 0; s < 256; ++s) {
            float aw = attn[s];
            cx0 += aw * hsf[(size_t)(s * 32 + row) * 256 + tid];
            cx1 += aw * hsb[(size_t)(s * 32 + row) * 256 + tid];
        }
        size_t base = (size_t)(t * 32 + row) * 768;
        comb16[base + tid] = f2bf(cx0);
        comb16[base + 256 + tid] = f2bf(cx1);
    }
}

// ---------- K3: henc_proj = enc @ henc_w + henc_b ----------
__global__ __launch_bounds__(256) void henc_kernel(const float* __restrict__ hsf, const float* __restrict__ hsb,
                                                   const float* __restrict__ hw, const float* __restrict__ hb,
                                                   float* __restrict__ henc) {
    __shared__ float Al[32][256];
    int r0 = blockIdx.x * 32;
    int tid = threadIdx.x;
    int rg = tid >> 5;
    int c = (tid & 31) * 4;
    float4 acc[4];
#pragma unroll
    for (int r = 0; r < 4; ++r) acc[r] = make_float4(0.f, 0.f, 0.f, 0.f);
    for (int kc = 0; kc < 2; ++kc) {
        const float* src_arr = kc ? hsb : hsf;
        {
            int ri = tid >> 3, cc = (tid & 7) * 32;
            int r = r0 + ri; int b = r >> 8, s = r & 255;
            const float4* sp = (const float4*)&src_arr[(size_t)(s * 32 + b) * 256 + cc];
            float4* dp = (float4*)&Al[ri][cc];
#pragma unroll
            for (int i = 0; i < 8; ++i) dp[i] = sp[i];
        }
        __syncthreads();
        for (int k = 0; k < 256; k += 4) {
            int kg = kc * 256 + k;
            float4 w0 = *(const float4*)&hw[(kg + 0) * 128 + c];
            float4 w1 = *(const float4*)&hw[(kg + 1) * 128 + c];
            float4 w2 = *(const float4*)&hw[(kg + 2) * 128 + c];
            float4 w3 = *(const float4*)&hw[(kg + 3) * 128 + c];
#pragma unroll
            for (int r = 0; r < 4; ++r) {
                float4 a = *(const float4*)&Al[rg * 4 + r][k];
                acc[r].x += a.x * w0.x + a.y * w1.x + a.z * w2.x + a.w * w3.x;
                acc[r].y += a.x * w0.y + a.y * w1.y + a.z * w2.y + a.w * w3.y;
                acc[r].z += a.x * w0.z + a.y * w1.z + a.z * w2.z + a.w * w3.z;
                acc[r].w += a.x * w0.w + a.y * w1.w + a.z * w2.w + a.w * w3.w;
            }
        }
        __syncthreads();
    }
    float4 b4 = *(const float4*)&hb[c];
#pragma unroll
    for (int r = 0; r < 4; ++r) {
        int row = r0 + rg * 4 + r;
        float4 v = make_float4(acc[r].x + b4.x, acc[r].y + b4.y, acc[r].z + b4.z, acc[r].w + b4.w);
        *(float4*)&henc[(size_t)row * 128 + c] = v;
    }
}

// ---------- K5: bf16 MFMA GEMM, both operands pre-packed bf16, m97 structure ----------
template <int MODE>
__global__ __launch_bounds__(256, 4) void gemm_bt(const unsigned short* __restrict__ A, int lda, int K,
                                                  const unsigned short* __restrict__ Bt, int ldb, int ncols,
                                                  const float* __restrict__ bias,
                                                  unsigned short* __restrict__ outC,
                                                  float* __restrict__ Pmax, float* __restrict__ Psum, int npart,
                                                  const int* __restrict__ targ, float* __restrict__ tlog) {
    __shared__ unsigned int AL[128 * 16];   // [row][16 dw], chunk c stored at c^((row>>1)&3)
    __shared__ unsigned int BL[128 * 16];   // [n][16 dw], same swizzle
    __shared__ int tgt_l[128];
    int per = (int)gridDim.x >> 3;
    int f = ((int)blockIdx.x & 7) * per + ((int)blockIdx.x >> 3);
    int ct = f >> 3, rt = f & 7;
    int tid = threadIdx.x;
    int lane = tid & 63, w = tid >> 6;
    int wr = w >> 1, wc = w & 1;
    if (MODE == 1 && tid < 128) {
        int row = rt * 128 + tid;
        int tt = row >> 5, bb = row & 31;
        tgt_l[tid] = (tt < 31) ? targ[bb * 32 + tt + 1] : -1;
    }
    f32x4 acc[4][4];
#pragma unroll
    for (int i = 0; i < 4; ++i)
#pragma unroll
        for (int j = 0; j < 4; ++j) acc[i][j] = (f32x4){0.f, 0.f, 0.f, 0.f};

    int P0 = tid,       r0 = P0 >> 2, c0 = (P0 & 3) ^ ((r0 >> 1) & 3);
    int P1 = 256 + tid, r1 = P1 >> 2, c1 = (P1 & 3) ^ ((r1 >> 1) & 3);
    const unsigned short* ag0 = A + (size_t)(rt * 128 + r0) * lda + c0 * 8;
    const unsigned short* ag1 = A + (size_t)(rt * 128 + r1) * lda + c1 * 8;
    const unsigned short* bg0 = Bt + (size_t)(ct * 128 + r0) * ldb + c0 * 8;
    const unsigned short* bg1 = Bt + (size_t)(ct * 128 + r1) * ldb + c1 * 8;
    unsigned int* adst0 = &AL[(size_t)(w * 64) * 4];          // wave-uniform bases
    unsigned int* adst1 = &AL[(size_t)(256 + w * 64) * 4];
    unsigned int* bdst0 = &BL[(size_t)(w * 64) * 4];
    unsigned int* bdst1 = &BL[(size_t)(256 + w * 64) * 4];

    int iters = K / 32;
    for (int it = 0; it < iters; ++it) {
        size_t k0 = (size_t)it * 32;
        __builtin_amdgcn_global_load_lds((GLDg*)(ag0 + k0), (GLDl*)adst0, 16, 0, 0);
        __builtin_amdgcn_global_load_lds((GLDg*)(ag1 + k0), (GLDl*)adst1, 16, 0, 0);
        __builtin_amdgcn_global_load_lds((GLDg*)(bg0 + k0), (GLDl*)bdst0, 16, 0, 0);
        __builtin_amdgcn_global_load_lds((GLDg*)(bg1 + k0), (GLDl*)bdst1, 16, 0, 0);
        __syncthreads();
        bf16x8 af[4];
#pragma unroll
        for (int i = 0; i < 4; ++i) {
            int r = wr * 64 + i * 16 + (lane & 15);
            int pos = (lane >> 4) ^ ((r >> 1) & 3);
            af[i] = *(const bf16x8*)&AL[r * 16 + pos * 4];
        }
#pragma unroll
        for (int j = 0; j < 4; ++j) {
            int n = wc * 64 + j * 16 + (lane & 15);
            int pos = (lane >> 4) ^ ((n >> 1) & 3);
            bf16x8 bfr = *(const bf16x8*)&BL[n * 16 + pos * 4];
#pragma unroll
            for (int i = 0; i < 4; ++i)
                acc[i][j] = __builtin_amdgcn_mfma_f32_16x16x32_bf16(af[i], bfr, acc[i][j], 0, 0, 0);
        }
        __syncthreads();
    }
    float bv[4]; bool vok[4];
#pragma unroll
    for (int j = 0; j < 4; ++j) {
        int col = ct * 128 + wc * 64 + j * 16 + (lane & 15);
        vok[j] = (col < ncols);
        bv[j] = vok[j] ? bias[col] : 0.0f;
    }
    if (MODE == 0) {
#pragma unroll
        for (int i = 0; i < 4; ++i)
#pragma unroll
            for (int reg = 0; reg < 4; ++reg) {
                int row = rt * 128 + wr * 64 + i * 16 + (lane >> 4) * 4 + reg;
#pragma unroll
                for (int j = 0; j < 4; ++j) {
                    int col = ct * 128 + wc * 64 + j * 16 + (lane & 15);
                    outC[(size_t)row * 4096 + col] = f2bf(acc[i][j][reg] + bv[j]);
                }
            }
    } else {
#pragma unroll
        for (int i = 0; i < 4; ++i)
#pragma unroll
            for (int reg = 0; reg < 4; ++reg) {
                int rowl = wr * 64 + i * 16 + (lane >> 4) * 4 + reg;
                int row = rt * 128 + rowl;
                int ntgt = tgt_l[rowl];
                float v[4];
                float m = -1e30f;
#pragma unroll
                for (int j = 0; j < 4; ++j) {
                    v[j] = vok[j] ? (acc[i][j][reg] + bv[j]) : -1e30f;
                    m = fmaxf(m, v[j]);
                }
#pragma unroll
                for (int j = 0; j < 4; ++j) {
                    int col = ct * 128 + wc * 64 + j * 16 + (lane & 15);
                    if (col == ntgt) tlog[row] = v[j];
                }
                m = fmaxf(m, __shfl_xor(m, 1));
                m = fmaxf(m, __shfl_xor(m, 2));
                m = fmaxf(m, __shfl_xor(m, 4));
                m = fmaxf(m, __shfl_xor(m, 8));
                float s = 0.0f;
#pragma unroll
                for (int j = 0; j < 4; ++j) s += __expf(v[j] - m);
                s += __shfl_xor(s, 1);
                s += __shfl_xor(s, 2);
                s += __shfl_xor(s, 4);
                s += __shfl_xor(s, 8);
                if ((lane & 15) == 0) {
                    Pmax[(size_t)row * npart + ct * 2 + wc] = m;
                    Psum[(size_t)row * npart + ct * 2 + wc] = s;
                }
            }
    }
}

// ---------- K5-fallback: fp32-B GEMM (used when workspace too small for lvwT) ----------
__global__ __launch_bounds__(256, 3) void gemm_big1(const unsigned short* __restrict__ A, int lda, int K,
                                                    const float* __restrict__ Bm, int Nstride,
                                                    const float* __restrict__ bias,
                                                    float* __restrict__ Pmax, float* __restrict__ Psum, int npart,
                                                    const int* __restrict__ targ, float* __restrict__ tlog) {
    __shared__ unsigned int AL[128 * 16];
    __shared__ unsigned int BL[128 * 16];
    __shared__ int tgt_l[128];
    int per = (int)gridDim.x >> 3;
    int f = ((int)blockIdx.x & 7) * per + ((int)blockIdx.x >> 3);
    int ct = f >> 3, rt = f & 7;
    int tid = threadIdx.x;
    int lane = tid & 63, w = tid >> 6;
    int wr = w >> 1, wc = w & 1;
    if (tid < 128) {
        int row = rt * 128 + tid;
        int tt = row >> 5, bb = row & 31;
        tgt_l[tid] = (tt < 31) ? targ[bb * 32 + tt + 1] : -1;
    }
    f32x4 acc[4][4];
#pragma unroll
    for (int i = 0; i < 4; ++i)
#pragma unroll
        for (int j = 0; j < 4; ++j) acc[i][j] = (f32x4){0.f, 0.f, 0.f, 0.f};
    int P0 = tid,       r0 = P0 >> 2, c0 = (P0 & 3) ^ ((r0 >> 1) & 3);
    int P1 = 256 + tid, r1 = P1 >> 2, c1 = (P1 & 3) ^ ((r1 >> 1) & 3);
    const unsigned short* ag0 = A + (size_t)(rt * 128 + r0) * lda + c0 * 8;
    const unsigned short* ag1 = A + (size_t)(rt * 128 + r1) * lda + c1 * 8;
    unsigned int* ldst0 = &AL[(size_t)(w * 64) * 4];
    unsigned int* ldst1 = &AL[(size_t)(256 + w * 64) * 4];
    int bn = tid & 127, bkh = tid >> 7;
    int coln = ct * 128 + bn;
    bool colok = (coln < Nstride);
    const float* bp = Bm + (size_t)(bkh * 16) * Nstride + (colok ? coln : 0);
    int bs = (bn >> 1) & 3;
    unsigned int* bw0 = &BL[bn * 16 + (((bkh * 2) ^ bs) * 4)];
    unsigned int* bw1 = &BL[bn * 16 + (((bkh * 2 + 1) ^ bs) * 4)];
    int iters = K / 32;
    for (int it = 0; it < iters; ++it) {
        size_t k0 = (size_t)it * 32;
        __builtin_amdgcn_global_load_lds((GLDg*)(ag0 + k0), (GLDl*)ldst0, 16, 0, 0);
        __builtin_amdgcn_global_load_lds((GLDg*)(ag1 + k0), (GLDl*)ldst1, 16, 0, 0);
        {
            const float* bq = bp + k0 * Nstride;
            unsigned int dw[8];
#pragma unroll
            for (int i = 0; i < 8; ++i) {
                float f0 = colok ? bq[(size_t)(2 * i) * Nstride] : 0.0f;
                float f1 = colok ? bq[(size_t)(2 * i + 1) * Nstride] : 0.0f;
                dw[i] = (unsigned int)f2bf(f0) | ((unsigned int)f2bf(f1) << 16);
            }
            *(uint4*)bw0 = make_uint4(dw[0], dw[1], dw[2], dw[3]);
            *(uint4*)bw1 = make_uint4(dw[4], dw[5], dw[6], dw[7]);
        }
        __syncthreads();
        bf16x8 af[4];
#pragma unroll
        for (int i = 0; i < 4; ++i) {
            int r = wr * 64 + i * 16 + (lane & 15);
            int pos = (lane >> 4) ^ ((r >> 1) & 3);
            af[i] = *(const bf16x8*)&AL[r * 16 + pos * 4];
        }
#pragma unroll
        for (int j = 0; j < 4; ++j) {
            int n = wc * 64 + j * 16 + (lane & 15);
            int pos = (lane >> 4) ^ ((n >> 1) & 3);
            bf16x8 bfr = *(const bf16x8*)&BL[n * 16 + pos * 4];
#pragma unroll
            for (int i = 0; i < 4; ++i)
                acc[i][j] = __builtin_amdgcn_mfma_f32_16x16x32_bf16(af[i], bfr, acc[i][j], 0, 0, 0);
        }
        __syncthreads();
    }
    float bv[4]; bool vok[4];
#pragma unroll
    for (int j = 0; j < 4; ++j) {
        int col = ct * 128 + wc * 64 + j * 16 + (lane & 15);
        vok[j] = (col < Nstride);
        bv[j] = vok[j] ? bias[col] : 0.0f;
    }
#pragma unroll
    for (int i = 0; i < 4; ++i)
#pragma unroll
        for (int reg = 0; reg < 4; ++reg) {
            int rowl = wr * 64 + i * 16 + (lane >> 4) * 4 + reg;
            int row = rt * 128 + rowl;
            int ntgt = tgt_l[rowl];
            float v[4];
            float m = -1e30f;
#pragma unroll
            for (int j = 0; j < 4; ++j) {
                v[j] = vok[j] ? (acc[i][j][reg] + bv[j]) : -1e30f;
                m = fmaxf(m, v[j]);
            }
#pragma unroll
            for (int j = 0; j < 4; ++j) {
                int col = ct * 128 + wc * 64 + j * 16 + (lane & 15);
                if (col == ntgt) tlog[row] = v[j];
            }
            m = fmaxf(m, __shfl_xor(m, 1));
            m = fmaxf(m, __shfl_xor(m, 2));
            m = fmaxf(m, __shfl_xor(m, 4));
            m = fmaxf(m, __shfl_xor(m, 8));
            float s = 0.0f;
#pragma unroll
            for (int j = 0; j < 4; ++j) s += __expf(v[j] - m);
            s += __shfl_xor(s, 1);
            s += __shfl_xor(s, 2);
            s += __shfl_xor(s, 4);
            s += __shfl_xor(s, 8);
            if ((lane & 15) == 0) {
                Pmax[(size_t)row * npart + ct * 2 + wc] = m;
                Psum[(size_t)row * npart + ct * 2 + wc] = s;
            }
        }
}

// ---------- K5d: per-row logsumexp + nll ----------
__global__ __launch_bounds__(256) void lse_nll(const float* __restrict__ Pmax, const float* __restrict__ Psum,
                                               const float* __restrict__ tlog, const int* __restrict__ targ,
                                               float* __restrict__ nll) {
    int row = blockIdx.x;
    int t = row >> 5, b = row & 31;
    int tid = threadIdx.x;
    __shared__ float rm[256];
    __shared__ float rs[256];
    float m = -1e30f;
    for (int i = tid; i < NPART; i += 256) m = fmaxf(m, Pmax[(size_t)row * NPART + i]);
    rm[tid] = m;
    __syncthreads();
    for (int off = 128; off; off >>= 1) {
        if (tid < off) rm[tid] = fmaxf(rm[tid], rm[tid + off]);
        __syncthreads();
    }
    m = rm[0];
    float s = 0.0f;
    for (int i = tid; i < NPART; i += 256)
        s += Psum[(size_t)row * NPART + i] * __expf(Pmax[(size_t)row * NPART + i] - m);
    rs[tid] = s;
    __syncthreads();
    for (int off = 128; off; off >>= 1) {
        if (tid < off) rs[tid] += rs[tid + off];
        __syncthreads();
    }
    if (tid == 0) {
        float lse = m + logf(rs[0]);
        float out = 0.0f;
        if (t < 31) {
            int tg = targ[b * 32 + t + 1];
            if (tg != 0) out = lse - tlog[row];
        }
        nll[row] = out;
    }
}

// ---------- K6: final reduce ----------
__global__ __launch_bounds__(256) void finloss(const float* __restrict__ nll, float* __restrict__ out) {
    __shared__ float red[256];
    int tid = threadIdx.x;
    float a = 0.0f;
    for (int i = tid; i < 1024; i += 256) a += nll[i];
    red[tid] = a;
    __syncthreads();
    for (int off = 128; off; off >>= 1) {
        if (tid < off) red[tid] += red[tid + off];
        __syncthreads();
    }
    if (tid == 0) out[0] = red[0] * (1.0f / 1024.0f);
}

extern "C" void kernel_launch(void* const* d_in, const int* in_sizes, int n_in,
                              void* d_out, int out_size, void* d_ws, size_t ws_size,
                              hipStream_t stream) {
    const int* inp = (const int*)d_in[0];
    const int* targ = (const int*)d_in[1];
    const float* emb = (const float*)d_in[2];
    const float* ekf = (const float*)d_in[3];
    const float* erf = (const float*)d_in[4];
    const float* ebf = (const float*)d_in[5];
    const float* ekb = (const float*)d_in[6];
    const float* erb = (const float*)d_in[7];
    const float* ebb = (const float*)d_in[8];
    const float* dk  = (const float*)d_in[9];
    const float* dr  = (const float*)d_in[10];
    const float* db  = (const float*)d_in[11];
    const float* hw  = (const float*)d_in[12];
    const float* hb  = (const float*)d_in[13];
    const float* sdw = (const float*)d_in[14];
    const float* sdb = (const float*)d_in[15];
    const float* vat = (const float*)d_in[16];
    const float* lfw = (const float*)d_in[17];
    const float* lfb = (const float*)d_in[18];
    const float* lvw = (const float*)d_in[19];
    const float* lvb = (const float*)d_in[20];

    float* ws = (float*)d_ws;
    float* xkf = ws + OFF_XKF;
    float* xkb = ws + OFF_XKB;
    float* xkd = ws + OFF_XKD;
    float* hsf = ws + OFF_HSF;
    float* hsb = ws + OFF_HSB;
    float* henc = ws + OFF_HENC;
    unsigned int* erpf = (unsigned int*)(ws + OFF_ERPF);
    unsigned int* erpb = (unsigned int*)(ws + OFF_ERPB);
    unsigned int* drp  = (unsigned int*)(ws + OFF_DRP);
    unsigned short* comb16 = (unsigned short*)(ws + OFF_COMB);
    unsigned short* fb16   = (unsigned short*)(ws + OFF_FB16);
    unsigned short* lfwT   = (unsigned short*)(ws + OFF_LFWT);
    unsigned short* lvwT   = (unsigned short*)(ws + OFF_LVWT);
    float* pmax = ws + OFF_PMAX;
    float* psum = ws + OFF_PSUM;
    float* tlog = ws + OFF_TLOG;
    float* nllb = ws + OFF_NLL;
    float* ct_all = ws + OFF_CT;

    bool big = (ws_size >= WS_NEED_BYTES);

    static bool attr_set = false;
    if (!attr_set) {
        hipFuncSetAttribute((const void*)lstm_cvt_fused,
                            hipFuncAttributeMaxDynamicSharedMemorySize, (int)ENC_LDS_BYTES);
        attr_set = true;
    }

    hipLaunchKernelGGL(pack_half_k, dim3(1536), dim3(256), 0, stream, erf, erb, dr, erpf, erpb, drp);
    hipLaunchKernelGGL(xgate_kernel, dim3(128, 8), dim3(256), 0, stream, emb, inp, 0, ekf, ebf, xkf);
    hipLaunchKernelGGL(xgate_kernel, dim3(128, 8), dim3(256), 0, stream, emb, inp, 0, ekb, ebb, xkb);
    hipLaunchKernelGGL(xgate_kernel, dim3(16, 8), dim3(256), 0, stream, emb, targ, 1, dk, db, xkd);
    // fused: enc_lstm (blk 0-63) + dec_lstm (blk 64-95) + lfw cvt (96-287) + lvw cvt (288+)
    {
        int nblk = big ? (288 + 12544) : 288;
        hipLaunchKernelGGL(lstm_cvt_fused, dim3(nblk), dim3(512), ENC_LDS_BYTES, stream,
                           xkf, xkb, erpf, erpb, hsf, hsb,
                           xkd, drp, ct_all, comb16,
                           lfw, lfwT, lvw, lvwT);
    }
    hipLaunchKernelGGL(henc_kernel, dim3(256), dim3(256), 0, stream, hsf, hsb, hw, hb, henc);
    hipLaunchKernelGGL(dec_attn, dim3(992), dim3(256), 0, stream,
                       ct_all, sdw, sdb, vat, henc, hsf, hsb, comb16);
    hipLaunchKernelGGL((gemm_bt<0>), dim3(256), dim3(256), 0, stream,
                       comb16, 768, 768, lfwT, 768, 4096, lfb, fb16,
                       (float*)nullptr, (float*)nullptr, 0, (const int*)nullptr, (float*)nullptr);
    if (big)
        hipLaunchKernelGGL((gemm_bt<1>), dim3(3128), dim3(256), 0, stream,
                           fb16, 4096, 4096, lvwT, 4096, 50000, lvb, (unsigned short*)nullptr,
                           pmax, psum, NPART, targ, tlog);
    else
        hipLaunchKernelGGL(gemm_big1, dim3(3128), dim3(256), 0, stream,
                           fb16, 4096, 4096, lvw, 50000, lvb, pmax, psum, NPART, targ, tlog);
    hipLaunchKernelGGL(lse_nll, dim3(1024), dim3(256), 0, stream, pmax, psum, tlog, targ, nllb);
    hipLaunchKernelGGL(finloss, dim3(1), dim3(256), 0, stream, nllb, (float*)d_out);
}

// Round 12
// 2117.571 us; speedup vs baseline: 1.4934x; 1.0158x over previous
//
#include <hip/hip_runtime.h>

#define DEV __device__ __forceinline__

typedef __attribute__((ext_vector_type(8))) short bf16x8;
typedef __attribute__((ext_vector_type(4))) float f32x4;
typedef __attribute__((ext_vector_type(2))) _Float16 h2_t;

typedef __attribute__((address_space(1))) const void GLDg;
typedef __attribute__((address_space(3))) void GLDl;

// ---------- constants ----------
static const int V = 50000, E = 128, H = 256, B = 32, S = 256, T = 32, FF = 4096;
static const int NCT = 391;           // ceil(50000/128)
static const int NPART = 782;         // 391 col tiles x 2 wave-cols
// workspace offsets (in floats)
static const size_t OFF_XKF  = 0;                     // S*B*4H = 8388608
static const size_t OFF_XKB  = 8388608;               // 8388608
static const size_t OFF_XKD  = 16777216;              // T*B*4H = 1048576
static const size_t OFF_HSF  = 17825792;              // S*B*H = 2097152
static const size_t OFF_HSB  = 19922944;              // 2097152
static const size_t OFF_HENC = 22020096;              // B*S*E = 1048576
static const size_t OFF_ERPF = 23068672;              // 131072 (uint)
static const size_t OFF_ERPB = 23199744;
static const size_t OFF_DRP  = 23330816;
static const size_t OFF_COMB = 23461888;              // 1024*768 ushort = 393216 floats
static const size_t OFF_FB16 = 23855104;              // 1024*4096 ushort = 2097152 floats
static const size_t OFF_LFWT = 25952256;              // 4096*768 ushort = 1572864 floats
static const size_t OFF_LVWT = 27525120;              // 50048*4096 ushort = 102498304 floats
static const size_t LVWT_FLOATS = 102498304;
static const size_t WS_NEED_BYTES = (OFF_LVWT + LVWT_FLOATS) * 4;   // ~520 MB
// scratch in the xkf region (dead after the fused LSTM kernel consumes xkf)
static const size_t OFF_PMAX = 0;                     // 1024*782 = 800768
static const size_t OFF_PSUM = 800768;
static const size_t OFF_TLOG = 1601536;
static const size_t OFF_CT   = 1603584;               // 31*32*256 = 253952 floats
static const size_t OFF_ACC  = 1857536;               // accumulator + counter (2 floats)

// dynamic LDS for the fused LSTM+cvt kernel: 2*64KB weights + 512B h2 + 4KB zg
static const size_t ENC_LDS_BYTES = 65536 * 2 + 512 + 4096;   // 136192

// ---------- helpers ----------
DEV float sigf(float x) { return 1.0f / (1.0f + __expf(-x)); }
DEV float tanh_(float x) {
    x = fminf(fmaxf(x, -20.0f), 20.0f);
    float e = __expf(2.0f * x);
    return (e - 1.0f) / (e + 1.0f);
}
DEV unsigned short f2bf(float f) {
    unsigned int u = __builtin_bit_cast(unsigned int, f);
    u += 0x7FFFu + ((u >> 16) & 1u);
    return (unsigned short)(u >> 16);
}
DEV float bf2f(unsigned short s) {
    unsigned int u = ((unsigned int)s) << 16;
    return __builtin_bit_cast(float, u);
}
DEV float dot2u(unsigned int a, unsigned int b, float c) {
#if __has_builtin(__builtin_amdgcn_fdot2)
    return __builtin_amdgcn_fdot2(__builtin_bit_cast(h2_t, a), __builtin_bit_cast(h2_t, b), c, false);
#else
    h2_t x = __builtin_bit_cast(h2_t, a), y = __builtin_bit_cast(h2_t, b);
    return c + (float)x[0] * (float)y[0] + (float)x[1] * (float)y[1];
#endif
}

// ---------- xgate body: gathered x@W + b  (M x 128)@(128 x 1024) ----------
DEV void xgate_body(const float* __restrict__ emb,
                    const int* __restrict__ tok_src, int dec_mode,
                    const float* __restrict__ wt,
                    const float* __restrict__ bias,
                    float* __restrict__ out, int bx, int by, int tid) {
    __shared__ float Al[64][128];
    __shared__ int tk[64];
    int r0 = bx * 64, c0b = by * 128;
    if (tid < 64) {
        int r = r0 + tid; int hi = r >> 5, b = r & 31; int token;
        if (dec_mode) token = (hi == 0) ? 2 : tok_src[b * 32 + hi];
        else          token = tok_src[b * 256 + hi];
        tk[tid] = token;
    }
    __syncthreads();
    {
        int ri = tid >> 2, cc = (tid & 3) * 32;
        const float4* src = (const float4*)&emb[(size_t)tk[ri] * 128 + cc];
        float4* dst = (float4*)&Al[ri][cc];
#pragma unroll
        for (int i = 0; i < 8; ++i) dst[i] = src[i];
    }
    __syncthreads();
    int rg = tid >> 5;
    int c = c0b + (tid & 31) * 4;
    float4 acc[8];
#pragma unroll
    for (int r = 0; r < 8; ++r) acc[r] = make_float4(0.f, 0.f, 0.f, 0.f);
    for (int k = 0; k < 128; k += 4) {
        float4 w0 = *(const float4*)&wt[(k + 0) * 1024 + c];
        float4 w1 = *(const float4*)&wt[(k + 1) * 1024 + c];
        float4 w2 = *(const float4*)&wt[(k + 2) * 1024 + c];
        float4 w3 = *(const float4*)&wt[(k + 3) * 1024 + c];
#pragma unroll
        for (int r = 0; r < 8; ++r) {
            float4 a = *(const float4*)&Al[rg * 8 + r][k];
            acc[r].x += a.x * w0.x + a.y * w1.x + a.z * w2.x + a.w * w3.x;
            acc[r].y += a.x * w0.y + a.y * w1.y + a.z * w2.y + a.w * w3.y;
            acc[r].z += a.x * w0.z + a.y * w1.z + a.z * w2.z + a.w * w3.z;
            acc[r].w += a.x * w0.w + a.y * w1.w + a.z * w2.w + a.w * w3.w;
        }
    }
    float4 b4 = *(const float4*)&bias[c];
#pragma unroll
    for (int r = 0; r < 8; ++r) {
        int row = r0 + rg * 8 + r;
        float4 v = make_float4(acc[r].x + b4.x, acc[r].y + b4.y, acc[r].z + b4.z, acc[r].w + b4.w);
        *(float4*)&out[(size_t)row * 1024 + c] = v;
    }
}

// ---------- K0: FUSED prep: pack recurrent weights + all three xgate GEMMs ----------
// blocks 0..1535: pack (col-major [c][k2] half2).  1536..2559: xgate enc-f.
// 2560..3583: xgate enc-b.  3584..3711: xgate dec.
__global__ __launch_bounds__(256) void prep_kernel(
        const float* __restrict__ erf, const float* __restrict__ erb, const float* __restrict__ dr,
        unsigned int* __restrict__ pf, unsigned int* __restrict__ pb, unsigned int* __restrict__ pd,
        const float* __restrict__ emb, const int* __restrict__ inp, const int* __restrict__ targ,
        const float* __restrict__ ekf, const float* __restrict__ ebf, float* __restrict__ xkf,
        const float* __restrict__ ekb, const float* __restrict__ ebb, float* __restrict__ xkb,
        const float* __restrict__ dk, const float* __restrict__ db, float* __restrict__ xkd) {
    int bid = blockIdx.x;
    int tid = threadIdx.x;
    if (bid < 1536) {
        int id = bid * 256 + tid;
        int which = id >> 17;
        int rem = id & 131071;
        const float* s = (which == 0) ? erf : (which == 1) ? erb : dr;
        unsigned int* o = (which == 0) ? pf : (which == 1) ? pb : pd;
        int cc = rem >> 7, k2 = rem & 127;            // o[cc*128+k2]
        float v0 = s[(2 * k2) * 1024 + cc];
        float v1 = s[(2 * k2 + 1) * 1024 + cc];
        h2_t h; h[0] = (_Float16)v0; h[1] = (_Float16)v1;
        o[rem] = __builtin_bit_cast(unsigned int, h);
    } else if (bid < 2560) {
        int f = bid - 1536;
        xgate_body(emb, inp, 0, ekf, ebf, xkf, f & 127, f >> 7, tid);
    } else if (bid < 3584) {
        int f = bid - 2560;
        xgate_body(emb, inp, 0, ekb, ebb, xkb, f & 127, f >> 7, tid);
    } else {
        int f = bid - 3584;
        xgate_body(emb, targ, 1, dk, db, xkd, f & 15, f >> 4, tid);
    }
}

// ---------- K2: FUSED enc_lstm (64 blk) + dec_lstm (32 blk) + weight cvt (rest) ----------
// 512 threads. LSTM: 2 cols/thread; weights split to FIT the 128-VGPR grant:
// quads 0-11 in regs (96 dwords, no spill), 12-19 in LDS (128KB), 20-31 streamed
// from L2 (384B/thread/step, contiguous). cvt: 256n x 64k float4 tiles.
extern __shared__ unsigned char dyn_lds[];
__global__ __launch_bounds__(512)
__attribute__((amdgpu_waves_per_eu(2, 2)))
void lstm_cvt_fused(
        const float* __restrict__ xkf, const float* __restrict__ xkb,
        const unsigned int* __restrict__ erpf, const unsigned int* __restrict__ erpb,
        float* __restrict__ hsf, float* __restrict__ hsb,
        const float* __restrict__ xkd, const unsigned int* __restrict__ drp,
        float* __restrict__ ct_all, unsigned short* __restrict__ comb16,
        const float* __restrict__ lfw, unsigned short* __restrict__ lfwT,
        const float* __restrict__ lvw, unsigned short* __restrict__ lvwT) {
    int bid = blockIdx.x;
    int tid = threadIdx.x;
    if (bid < 96) {
        // ----- LSTM recurrence (enc: bid<64, dec: 64..95) -----
        int is_dec = (bid >= 64);
        int dir = is_dec ? 0 : (bid >> 5);
        int row = is_dec ? (bid - 64) : (bid & 31);
        const float* xk = is_dec ? xkd : (dir ? xkb : xkf);
        const unsigned int* erp = is_dec ? drp : (dir ? erpb : erpf);
        float* hs = dir ? hsb : hsf;
        int nsteps = is_dec ? 31 : 256;
        int ca = 2 * tid;
        uint4* wlA = (uint4*)dyn_lds;                      // [8][512]
        uint4* wlB = (uint4*)(dyn_lds + 65536);            // [8][512]
        unsigned int* h2 = (unsigned int*)(dyn_lds + 131072);
        float* zg = (float*)(dyn_lds + 131072 + 512);

        const uint4* pa = (const uint4*)&erp[(size_t)ca * 128];        // 32 uint4/col
        const uint4* pb = (const uint4*)&erp[(size_t)(ca + 1) * 128];
        uint4 wa[12], wb[12];
#pragma unroll
        for (int i = 0; i < 12; ++i) { wa[i] = pa[i]; wb[i] = pb[i]; }
#pragma unroll
        for (int i = 0; i < 12; ++i) {
            asm volatile("" : "+v"(wa[i].x), "+v"(wa[i].y), "+v"(wa[i].z), "+v"(wa[i].w),
                             "+v"(wb[i].x), "+v"(wb[i].y), "+v"(wb[i].z), "+v"(wb[i].w));
        }
#pragma unroll
        for (int j = 0; j < 8; ++j) { wlA[j * 512 + tid] = pa[12 + j]; wlB[j * 512 + tid] = pb[12 + j]; }
        const uint4* sa = pa + 20;                         // streamed quads 20..31
        const uint4* sb = pb + 20;
        if (tid < 128) h2[tid] = 0u;
        float c_reg = 0.0f;
        __syncthreads();
        int s0 = (!is_dec && dir) ? (nsteps - 1) : 0;
        float2 xcur = *(const float2*)&xk[(size_t)(s0 * 32 + row) * 1024 + ca];
        for (int si = 0; si < nsteps; ++si) {
            int s = (!is_dec && dir) ? (nsteps - 1 - si) : si;
            float2 xnext = make_float2(0.f, 0.f);
            if (si + 1 < nsteps) {
                int sn = (!is_dec && dir) ? (nsteps - 2 - si) : (si + 1);
                xnext = *(const float2*)&xk[(size_t)(sn * 32 + row) * 1024 + ca];
            }
            float acc0 = xcur.x, acc1 = xcur.y;
            // regs: k2 quads 0..11  (h2[0..47])
#pragma unroll
            for (int i = 0; i < 12; ++i) {
                uint4 hv = *(const uint4*)&h2[4 * i];
                acc0 = dot2u(hv.x, wa[i].x, acc0);
                acc0 = dot2u(hv.y, wa[i].y, acc0);
                acc0 = dot2u(hv.z, wa[i].z, acc0);
                acc0 = dot2u(hv.w, wa[i].w, acc0);
                acc1 = dot2u(hv.x, wb[i].x, acc1);
                acc1 = dot2u(hv.y, wb[i].y, acc1);
                acc1 = dot2u(hv.z, wb[i].z, acc1);
                acc1 = dot2u(hv.w, wb[i].w, acc1);
            }
            // LDS: quads 12..19  (h2[48..79])
#pragma unroll
            for (int j = 0; j < 8; ++j) {
                uint4 hv = *(const uint4*)&h2[48 + 4 * j];
                uint4 qa = wlA[j * 512 + tid];
                uint4 qb = wlB[j * 512 + tid];
                acc0 = dot2u(hv.x, qa.x, acc0);
                acc0 = dot2u(hv.y, qa.y, acc0);
                acc0 = dot2u(hv.z, qa.z, acc0);
                acc0 = dot2u(hv.w, qa.w, acc0);
                acc1 = dot2u(hv.x, qb.x, acc1);
                acc1 = dot2u(hv.y, qb.y, acc1);
                acc1 = dot2u(hv.z, qb.z, acc1);
                acc1 = dot2u(hv.w, qb.w, acc1);
            }
            // L2 stream: quads 20..31  (h2[80..127])
#pragma unroll
            for (int m = 0; m < 12; ++m) {
                uint4 hv = *(const uint4*)&h2[80 + 4 * m];
                uint4 qa = sa[m];
                uint4 qb = sb[m];
                acc0 = dot2u(hv.x, qa.x, acc0);
                acc0 = dot2u(hv.y, qa.y, acc0);
                acc0 = dot2u(hv.z, qa.z, acc0);
                acc0 = dot2u(hv.w, qa.w, acc0);
                acc1 = dot2u(hv.x, qb.x, acc1);
                acc1 = dot2u(hv.y, qb.y, acc1);
                acc1 = dot2u(hv.z, qb.z, acc1);
                acc1 = dot2u(hv.w, qb.w, acc1);
            }
            *(float2*)&zg[ca] = make_float2(acc0, acc1);
            __syncthreads();
            if (tid < 256) {
                float ii = zg[tid], ff = zg[tid + 256], gg = zg[tid + 512], oo = zg[tid + 768];
                c_reg = sigf(ff) * c_reg + sigf(ii) * tanh_(gg);
                float h = sigf(oo) * tanh_(c_reg);
                ((_Float16*)h2)[tid] = (_Float16)h;
                if (is_dec) {
                    ct_all[(size_t)(s * 32 + row) * 256 + tid] = c_reg;
                    comb16[(size_t)(s * 32 + row) * 768 + 512 + tid] = f2bf(c_reg);
                } else {
                    hs[(size_t)(s * 32 + row) * 256 + tid] = h;
                }
            }
            __syncthreads();
            xcur = xnext;
        }
        if (is_dec) {       // zero pad rows 992..1023 of comb16
            size_t base = (size_t)(31 * 32 + row) * 768;
            for (int j = tid; j < 768; j += 512) comb16[base + j] = 0;
        }
    } else {
        // ----- weight convert+transpose, 256n x 64k tile per block, float4 loads -----
        const float* src; unsigned short* dst; int N, ldd, nb, kb, nmax;
        if (bid < 96 + 192) {
            int f2 = bid - 96;                    // lfw: 16 n-tiles x 12 k-tiles
            src = lfw; dst = lfwT; N = 4096; ldd = 768; nmax = 4096;
            nb = (f2 & 15) * 256; kb = (f2 >> 4) * 64;
        } else {
            int f3 = bid - 288;                   // lvw: 196 n-tiles x 64 k-tiles
            src = lvw; dst = lvwT; N = 50000; ldd = 4096; nmax = 50048;
            int nbi = f3 % 196, kbi = f3 / 196;
            nb = nbi * 256; kb = kbi * 64;
        }
        unsigned int* l32 = (unsigned int*)dyn_lds;        // [32 kpair][260 dw]
        int nl = tid & 63, kg = tid >> 6;                  // kg 0..7, each: 8 k-rows
        float4 v[8];
        if (nb + 256 <= N) {
            const float* sp = src + (size_t)(kb + kg * 8) * N + nb + nl * 4;
#pragma unroll
            for (int j = 0; j < 8; ++j) v[j] = *(const float4*)(sp + (size_t)j * N);
        } else {
#pragma unroll
            for (int j = 0; j < 8; ++j) {
                int n0 = nb + nl * 4;
                const float* rp = src + (size_t)(kb + kg * 8 + j) * N;
                v[j].x = (n0 + 0 < N) ? rp[n0 + 0] : 0.0f;
                v[j].y = (n0 + 1 < N) ? rp[n0 + 1] : 0.0f;
                v[j].z = (n0 + 2 < N) ? rp[n0 + 2] : 0.0f;
                v[j].w = (n0 + 3 < N) ? rp[n0 + 3] : 0.0f;
            }
        }
#pragma unroll
        for (int p = 0; p < 4; ++p) {           // k-pair (2p, 2p+1)
            unsigned int d0 = (unsigned int)f2bf(v[2 * p].x) | ((unsigned int)f2bf(v[2 * p + 1].x) << 16);
            unsigned int d1 = (unsigned int)f2bf(v[2 * p].y) | ((unsigned int)f2bf(v[2 * p + 1].y) << 16);
            unsigned int d2 = (unsigned int)f2bf(v[2 * p].z) | ((unsigned int)f2bf(v[2 * p + 1].z) << 16);
            unsigned int d3 = (unsigned int)f2bf(v[2 * p].w) | ((unsigned int)f2bf(v[2 * p + 1].w) << 16);
            *(uint4*)&l32[(size_t)(kg * 4 + p) * 260 + nl * 4] = make_uint4(d0, d1, d2, d3);
        }
        __syncthreads();
#pragma unroll
        for (int i = 0; i < 4; ++i) {
            int cid = i * 512 + tid;
            int nloc = cid >> 3, kc = cid & 7;
            int n = nb + nloc;
            if (n < nmax) {
                unsigned int u0 = l32[(size_t)(kc * 4 + 0) * 260 + nloc];
                unsigned int u1 = l32[(size_t)(kc * 4 + 1) * 260 + nloc];
                unsigned int u2 = l32[(size_t)(kc * 4 + 2) * 260 + nloc];
                unsigned int u3 = l32[(size_t)(kc * 4 + 3) * 260 + nloc];
                *(uint4*)&dst[(size_t)n * ldd + kb + kc * 8] = make_uint4(u0, u1, u2, u3);
            }
        }
    }
}

// ---------- K2c: decoder attention, all (t,row) in parallel; also zeroes loss accum ----------
__global__ __launch_bounds__(256) void dec_attn(const float* __restrict__ ct_all,
                                                const float* __restrict__ sdw, const float* __restrict__ sdb,
                                                const float* __restrict__ vatt,
                                                const float* __restrict__ henc,
                                                const float* __restrict__ hsf, const float* __restrict__ hsb,
                                                unsigned short* __restrict__ comb16,
                                                float* __restrict__ accum) {
    int per = (int)gridDim.x >> 3;                    // 124
    int f = ((int)blockIdx.x & 7) * per + ((int)blockIdx.x >> 3);
    int row = f / 31, t = f - row * 31;
    int tid = threadIdx.x;
    if (blockIdx.x == 0 && tid < 2) accum[tid] = 0.0f;   // accum + counter, re-zeroed each replay
    __shared__ float c_l[256];
    __shared__ float catt[128];
    __shared__ float attn[256];
    __shared__ float red[256];
    __shared__ float vat[128];
    __shared__ float part[256];
    c_l[tid] = ct_all[(size_t)(t * 32 + row) * 256 + tid];
    if (tid < 128) vat[tid] = vatt[tid];
    __syncthreads();
    {
        int col = tid & 127, k0 = (tid >> 7) * 128;
        float aa = 0.0f;
#pragma unroll 4
        for (int k = 0; k < 128; ++k) aa += c_l[k0 + k] * sdw[(size_t)(k0 + k) * 128 + col];
        part[tid] = aa;
    }
    __syncthreads();
    if (tid < 128) catt[tid] = part[tid] + part[tid + 128] + sdb[tid];
    __syncthreads();
    {
        const float4* hp = (const float4*)&henc[(size_t)(row * 256 + tid) * 128];
        float aa = 0.0f;
#pragma unroll 4
        for (int e4 = 0; e4 < 32; ++e4) {
            float4 h4 = hp[e4];
            int e = 4 * e4;
            aa += tanh_(h4.x + catt[e + 0]) * vat[e + 0];
            aa += tanh_(h4.y + catt[e + 1]) * vat[e + 1];
            aa += tanh_(h4.z + catt[e + 2]) * vat[e + 2];
            aa += tanh_(h4.w + catt[e + 3]) * vat[e + 3];
        }
        attn[tid] = aa;
    }
    __syncthreads();
    red[tid] = attn[tid];
    __syncthreads();
    for (int off = 128; off; off >>= 1) {
        if (tid < off) red[tid] = fmaxf(red[tid], red[tid + off]);
        __syncthreads();
    }
    float mx = red[0];
    __syncthreads();
    float ex = __expf(attn[tid] - mx);
    red[tid] = ex;
    __syncthreads();
    for (int off = 128; off; off >>= 1) {
        if (tid < off) red[tid] += red[tid + off];
        __syncthreads();
    }
    float inv = 1.0f / red[0];
    __syncthreads();
    attn[tid] = ex * inv;
    __syncthreads();
    {
        float cx0 = 0.0f, cx1 = 0.0f;
#pragma unroll 4
        for (int s = 0; s < 256; ++s) {
            float aw = attn[s];
            cx0 += aw * hsf[(size_t)(s * 32 + row) * 256 + tid];
            cx1 += aw * hsb[(size_t)(s * 32 + row) * 256 + tid];
        }
        size_t base = (size_t)(t * 32 + row) * 768;
        comb16[base + tid] = f2bf(cx0);
        comb16[base + 256 + tid] = f2bf(cx1);
    }
}

// ---------- K3: henc_proj = enc @ henc_w + henc_b ----------
__global__ __launch_bounds__(256) void henc_kernel(const float* __restrict__ hsf, const float* __restrict__ hsb,
                                                   const float* __restrict__ hw, const float* __restrict__ hb,
                                                   float* __restrict__ henc) {
    __shared__ float Al[32][256];
    int r0 = blockIdx.x * 32;
    int tid = threadIdx.x;
    int rg = tid >> 5;
    int c = (tid & 31) * 4;
    float4 acc[4];
#pragma unroll
    for (int r = 0; r < 4; ++r) acc[r] = make_float4(0.f, 0.f, 0.f, 0.f);
    for (int kc = 0; kc < 2; ++kc) {
        const float* src_arr = kc ? hsb : hsf;
        {
            int ri = tid >> 3, cc = (tid & 7) * 32;
            int r = r0 + ri; int b = r >> 8, s = r & 255;
            const float4* sp = (const float4*)&src_arr[(size_t)(s * 32 + b) * 256 + cc];
            float4* dp = (float4*)&Al[ri][cc];
#pragma unroll
            for (int i = 0; i < 8; ++i) dp[i] = sp[i];
        }
        __syncthreads();
        for (int k = 0; k < 256; k += 4) {
            int kg = kc * 256 + k;
            float4 w0 = *(const float4*)&hw[(kg + 0) * 128 + c];
            float4 w1 = *(const float4*)&hw[(kg + 1) * 128 + c];
            float4 w2 = *(const float4*)&hw[(kg + 2) * 128 + c];
            float4 w3 = *(const float4*)&hw[(kg + 3) * 128 + c];
#pragma unroll
            for (int r = 0; r < 4; ++r) {
                float4 a = *(const float4*)&Al[rg * 4 + r][k];
                acc[r].x += a.x * w0.x + a.y * w1.x + a.z * w2.x + a.w * w3.x;
                acc[r].y += a.x * w0.y + a.y * w1.y + a.z * w2.y + a.w * w3.y;
                acc[r].z += a.x * w0.z + a.y * w1.z + a.z * w2.z + a.w * w3.z;
                acc[r].w += a.x * w0.w + a.y * w1.w + a.z * w2.w + a.w * w3.w;
            }
        }
        __syncthreads();
    }
    float4 b4 = *(const float4*)&hb[c];
#pragma unroll
    for (int r = 0; r < 4; ++r) {
        int row = r0 + rg * 4 + r;
        float4 v = make_float4(acc[r].x + b4.x, acc[r].y + b4.y, acc[r].z + b4.z, acc[r].w + b4.w);
        *(float4*)&henc[(size_t)row * 128 + c] = v;
    }
}

// ---------- K5: bf16 MFMA GEMM, both operands pre-packed bf16, m97 structure ----------
template <int MODE>
__global__ __launch_bounds__(256, 4) void gemm_bt(const unsigned short* __restrict__ A, int lda, int K,
                                                  const unsigned short* __restrict__ Bt, int ldb, int ncols,
                                                  const float* __restrict__ bias,
                                                  unsigned short* __restrict__ outC,
                                                  float* __restrict__ Pmax, float* __restrict__ Psum, int npart,
                                                  const int* __restrict__ targ, float* __restrict__ tlog) {
    __shared__ unsigned int AL[128 * 16];   // [row][16 dw], chunk c stored at c^((row>>1)&3)
    __shared__ unsigned int BL[128 * 16];   // [n][16 dw], same swizzle
    __shared__ int tgt_l[128];
    int per = (int)gridDim.x >> 3;
    int f = ((int)blockIdx.x & 7) * per + ((int)blockIdx.x >> 3);
    int ct = f >> 3, rt = f & 7;
    int tid = threadIdx.x;
    int lane = tid & 63, w = tid >> 6;
    int wr = w >> 1, wc = w & 1;
    if (MODE == 1 && tid < 128) {
        int row = rt * 128 + tid;
        int tt = row >> 5, bb = row & 31;
        tgt_l[tid] = (tt < 31) ? targ[bb * 32 + tt + 1] : -1;
    }
    f32x4 acc[4][4];
#pragma unroll
    for (int i = 0; i < 4; ++i)
#pragma unroll
        for (int j = 0; j < 4; ++j) acc[i][j] = (f32x4){0.f, 0.f, 0.f, 0.f};

    int P0 = tid,       r0 = P0 >> 2, c0 = (P0 & 3) ^ ((r0 >> 1) & 3);
    int P1 = 256 + tid, r1 = P1 >> 2, c1 = (P1 & 3) ^ ((r1 >> 1) & 3);
    const unsigned short* ag0 = A + (size_t)(rt * 128 + r0) * lda + c0 * 8;
    const unsigned short* ag1 = A + (size_t)(rt * 128 + r1) * lda + c1 * 8;
    const unsigned short* bg0 = Bt + (size_t)(ct * 128 + r0) * ldb + c0 * 8;
    const unsigned short* bg1 = Bt + (size_t)(ct * 128 + r1) * ldb + c1 * 8;
    unsigned int* adst0 = &AL[(size_t)(w * 64) * 4];          // wave-uniform bases
    unsigned int* adst1 = &AL[(size_t)(256 + w * 64) * 4];
    unsigned int* bdst0 = &BL[(size_t)(w * 64) * 4];
    unsigned int* bdst1 = &BL[(size_t)(256 + w * 64) * 4];

    int iters = K / 32;
    for (int it = 0; it < iters; ++it) {
        size_t k0 = (size_t)it * 32;
        __builtin_amdgcn_global_load_lds((GLDg*)(ag0 + k0), (GLDl*)adst0, 16, 0, 0);
        __builtin_amdgcn_global_load_lds((GLDg*)(ag1 + k0), (GLDl*)adst1, 16, 0, 0);
        __builtin_amdgcn_global_load_lds((GLDg*)(bg0 + k0), (GLDl*)bdst0, 16, 0, 0);
        __builtin_amdgcn_global_load_lds((GLDg*)(bg1 + k0), (GLDl*)bdst1, 16, 0, 0);
        __syncthreads();
        bf16x8 af[4];
#pragma unroll
        for (int i = 0; i < 4; ++i) {
            int r = wr * 64 + i * 16 + (lane & 15);
            int pos = (lane >> 4) ^ ((r >> 1) & 3);
            af[i] = *(const bf16x8*)&AL[r * 16 + pos * 4];
        }
#pragma unroll
        for (int j = 0; j < 4; ++j) {
            int n = wc * 64 + j * 16 + (lane & 15);
            int pos = (lane >> 4) ^ ((n >> 1) & 3);
            bf16x8 bfr = *(const bf16x8*)&BL[n * 16 + pos * 4];
#pragma unroll
            for (int i = 0; i < 4; ++i)
                acc[i][j] = __builtin_amdgcn_mfma_f32_16x16x32_bf16(af[i], bfr, acc[i][j], 0, 0, 0);
        }
        __syncthreads();
    }
    float bv[4]; bool vok[4];
#pragma unroll
    for (int j = 0; j < 4; ++j) {
        int col = ct * 128 + wc * 64 + j * 16 + (lane & 15);
        vok[j] = (col < ncols);
        bv[j] = vok[j] ? bias[col] : 0.0f;
    }
    if (MODE == 0) {
#pragma unroll
        for (int i = 0; i < 4; ++i)
#pragma unroll
            for (int reg = 0; reg < 4; ++reg) {
                int row = rt * 128 + wr * 64 + i * 16 + (lane >> 4) * 4 + reg;
#pragma unroll
                for (int j = 0; j < 4; ++j) {
                    int col = ct * 128 + wc * 64 + j * 16 + (lane & 15);
                    outC[(size_t)row * 4096 + col] = f2bf(acc[i][j][reg] + bv[j]);
                }
            }
    } else {
#pragma unroll
        for (int i = 0; i < 4; ++i)
#pragma unroll
            for (int reg = 0; reg < 4; ++reg) {
                int rowl = wr * 64 + i * 16 + (lane >> 4) * 4 + reg;
                int row = rt * 128 + rowl;
                int ntgt = tgt_l[rowl];
                float v[4];
                float m = -1e30f;
#pragma unroll
                for (int j = 0; j < 4; ++j) {
                    v[j] = vok[j] ? (acc[i][j][reg] + bv[j]) : -1e30f;
                    m = fmaxf(m, v[j]);
                }
#pragma unroll
                for (int j = 0; j < 4; ++j) {
                    int col = ct * 128 + wc * 64 + j * 16 + (lane & 15);
                    if (col == ntgt) tlog[row] = v[j];
                }
                m = fmaxf(m, __shfl_xor(m, 1));
                m = fmaxf(m, __shfl_xor(m, 2));
                m = fmaxf(m, __shfl_xor(m, 4));
                m = fmaxf(m, __shfl_xor(m, 8));
                float s = 0.0f;
#pragma unroll
                for (int j = 0; j < 4; ++j) s += __expf(v[j] - m);
                s += __shfl_xor(s, 1);
                s += __shfl_xor(s, 2);
                s += __shfl_xor(s, 4);
                s += __shfl_xor(s, 8);
                if ((lane & 15) == 0) {
                    Pmax[(size_t)row * npart + ct * 2 + wc] = m;
                    Psum[(size_t)row * npart + ct * 2 + wc] = s;
                }
            }
    }
}

// ---------- K5-fallback: fp32-B GEMM (used when workspace too small for lvwT) ----------
__global__ __launch_bounds__(256, 3) void gemm_big1(const unsigned short* __restrict__ A, int lda, int K,
                                                    const float* __restrict__ Bm, int Nstride,
                                                    const float* __restrict__ bias,
                                                    float* __restrict__ Pmax, float* __restrict__ Psum, int npart,
                                                    const int* __restrict__ targ, float* __restrict__ tlog) {
    __shared__ unsigned int AL[128 * 16];
    __shared__ unsigned int BL[128 * 16];
    __shared__ int tgt_l[128];
    int per = (int)gridDim.x >> 3;
    int f = ((int)blockIdx.x & 7) * per + ((int)blockIdx.x >> 3);
    int ct = f >> 3, rt = f & 7;
    int tid = threadIdx.x;
    int lane = tid & 63, w = tid >> 6;
    int wr = w >> 1, wc = w & 1;
    if (tid < 128) {
        int row = rt * 128 + tid;
        int tt = row >> 5, bb = row & 31;
        tgt_l[tid] = (tt < 31) ? targ[bb * 32 + tt + 1] : -1;
    }
    f32x4 acc[4][4];
#pragma unroll
    for (int i = 0; i < 4; ++i)
#pragma unroll
        for (int j = 0; j < 4; ++j) acc[i][j] = (f32x4){0.f, 0.f, 0.f, 0.f};
    int P0 = tid,       r0 = P0 >> 2, c0 = (P0 & 3) ^ ((r0 >> 1) & 3);
    int P1 = 256 + tid, r1 = P1 >> 2, c1 = (P1 & 3) ^ ((r1 >> 1) & 3);
    const unsigned short* ag0 = A + (size_t)(rt * 128 + r0) * lda + c0 * 8;
    const unsigned short* ag1 = A + (size_t)(rt * 128 + r1) * lda + c1 * 8;
    unsigned int* ldst0 = &AL[(size_t)(w * 64) * 4];
    unsigned int* ldst1 = &AL[(size_t)(256 + w * 64) * 4];
    int bn = tid & 127, bkh = tid >> 7;
    int coln = ct * 128 + bn;
    bool colok = (coln < Nstride);
    const float* bp = Bm + (size_t)(bkh * 16) * Nstride + (colok ? coln : 0);
    int bs = (bn >> 1) & 3;
    unsigned int* bw0 = &BL[bn * 16 + (((bkh * 2) ^ bs) * 4)];
    unsigned int* bw1 = &BL[bn * 16 + (((bkh * 2 + 1) ^ bs) * 4)];
    int iters = K / 32;
    for (int it = 0; it < iters; ++it) {
        size_t k0 = (size_t)it * 32;
        __builtin_amdgcn_global_load_lds((GLDg*)(ag0 + k0), (GLDl*)ldst0, 16, 0, 0);
        __builtin_amdgcn_global_load_lds((GLDg*)(ag1 + k0), (GLDl*)ldst1, 16, 0, 0);
        {
            const float* bq = bp + k0 * Nstride;
            unsigned int dw[8];
#pragma unroll
            for (int i = 0; i < 8; ++i) {
                float f0 = colok ? bq[(size_t)(2 * i) * Nstride] : 0.0f;
                float f1 = colok ? bq[(size_t)(2 * i + 1) * Nstride] : 0.0f;
                dw[i] = (unsigned int)f2bf(f0) | ((unsigned int)f2bf(f1) << 16);
            }
            *(uint4*)bw0 = make_uint4(dw[0], dw[1], dw[2], dw[3]);
            *(uint4*)bw1 = make_uint4(dw[4], dw[5], dw[6], dw[7]);
        }
        __syncthreads();
        bf16x8 af[4];
#pragma unroll
        for (int i = 0; i < 4; ++i) {
            int r = wr * 64 + i * 16 + (lane & 15);
            int pos = (lane >> 4) ^ ((r >> 1) & 3);
            af[i] = *(const bf16x8*)&AL[r * 16 + pos * 4];
        }
#pragma unroll
        for (int j = 0; j < 4; ++j) {
            int n = wc * 64 + j * 16 + (lane & 15);
            int pos = (lane >> 4) ^ ((n >> 1) & 3);
            bf16x8 bfr = *(const bf16x8*)&BL[n * 16 + pos * 4];
#pragma unroll
            for (int i = 0; i < 4; ++i)
                acc[i][j] = __builtin_amdgcn_mfma_f32_16x16x32_bf16(af[i], bfr, acc[i][j], 0, 0, 0);
        }
        __syncthreads();
    }
    float bv[4]; bool vok[4];
#pragma unroll
    for (int j = 0; j < 4; ++j) {
        int col = ct * 128 + wc * 64 + j * 16 + (lane & 15);
        vok[j] = (col < Nstride);
        bv[j] = vok[j] ? bias[col] : 0.0f;
    }
#pragma unroll
    for (int i = 0; i < 4; ++i)
#pragma unroll
        for (int reg = 0; reg < 4; ++reg) {
            int rowl = wr * 64 + i * 16 + (lane >> 4) * 4 + reg;
            int row = rt * 128 + rowl;
            int ntgt = tgt_l[rowl];
            float v[4];
            float m = -1e30f;
#pragma unroll
            for (int j = 0; j < 4; ++j) {
                v[j] = vok[j] ? (acc[i][j][reg] + bv[j]) : -1e30f;
                m = fmaxf(m, v[j]);
            }
#pragma unroll
            for (int j = 0; j < 4; ++j) {
                int col = ct * 128 + wc * 64 + j * 16 + (lane & 15);
                if (col == ntgt) tlog[row] = v[j];
            }
            m = fmaxf(m, __shfl_xor(m, 1));
            m = fmaxf(m, __shfl_xor(m, 2));
            m = fmaxf(m, __shfl_xor(m, 4));
            m = fmaxf(m, __shfl_xor(m, 8));
            float s = 0.0f;
#pragma unroll
            for (int j = 0; j < 4; ++j) s += __expf(v[j] - m);
            s += __shfl_xor(s, 1);
            s += __shfl_xor(s, 2);
            s += __shfl_xor(s, 4);
            s += __shfl_xor(s, 8);
            if ((lane & 15) == 0) {
                Pmax[(size_t)row * npart + ct * 2 + wc] = m;
                Psum[(size_t)row * npart + ct * 2 + wc] = s;
            }
        }
}

// ---------- K5d: per-row logsumexp + nll + fused final reduce (atomic) ----------
__global__ __launch_bounds__(256) void lse_nll(const float* __restrict__ Pmax, const float* __restrict__ Psum,
                                               const float* __restrict__ tlog, const int* __restrict__ targ,
                                               float* __restrict__ accum, float* __restrict__ dout) {
    int row = blockIdx.x;
    int t = row >> 5, b = row & 31;
    int tid = threadIdx.x;
    __shared__ float rm[256];
    __shared__ float rs[256];
    float m = -1e30f;
    for (int i = tid; i < NPART; i += 256) m = fmaxf(m, Pmax[(size_t)row * NPART + i]);
    rm[tid] = m;
    __syncthreads();
    for (int off = 128; off; off >>= 1) {
        if (tid < off) rm[tid] = fmaxf(rm[tid], rm[tid + off]);
        __syncthreads();
    }
    m = rm[0];
    float s = 0.0f;
    for (int i = tid; i < NPART; i += 256)
        s += Psum[(size_t)row * NPART + i] * __expf(Pmax[(size_t)row * NPART + i] - m);
    rs[tid] = s;
    __syncthreads();
    for (int off = 128; off; off >>= 1) {
        if (tid < off) rs[tid] += rs[tid + off];
        __syncthreads();
    }
    if (tid == 0) {
        float lse = m + logf(rs[0]);
        float out = 0.0f;
        if (t < 31) {
            int tg = targ[b * 32 + t + 1];
            if (tg != 0) out = lse - tlog[row];
        }
        atomicAdd(accum, out * (1.0f / 1024.0f));
        __threadfence();
        unsigned int prev = atomicAdd((unsigned int*)(accum + 1), 1u);
        if (prev == 1023u) {
            __threadfence();
            float tot = atomicAdd(accum, 0.0f);   // coherent read via atomic RMW
            dout[0] = tot;
        }
    }
}

extern "C" void kernel_launch(void* const* d_in, const int* in_sizes, int n_in,
                              void* d_out, int out_size, void* d_ws, size_t ws_size,
                              hipStream_t stream) {
    const int* inp = (const int*)d_in[0];
    const int* targ = (const int*)d_in[1];
    const float* emb = (const float*)d_in[2];
    const float* ekf = (const float*)d_in[3];
    const float* erf = (const float*)d_in[4];
    const float* ebf = (const float*)d_in[5];
    const float* ekb = (const float*)d_in[6];
    const float* erb = (const float*)d_in[7];
    const float* ebb = (const float*)d_in[8];
    const float* dk  = (const float*)d_in[9];
    const float* dr  = (const float*)d_in[10];
    const float* db  = (const float*)d_in[11];
    const float* hw  = (const float*)d_in[12];
    const float* hb  = (const float*)d_in[13];
    const float* sdw = (const float*)d_in[14];
    const float* sdb = (const float*)d_in[15];
    const float* vat = (const float*)d_in[16];
    const float* lfw = (const float*)d_in[17];
    const float* lfb = (const float*)d_in[18];
    const float* lvw = (const float*)d_in[19];
    const float* lvb = (const float*)d_in[20];

    float* ws = (float*)d_ws;
    float* xkf = ws + OFF_XKF;
    float* xkb = ws + OFF_XKB;
    float* xkd = ws + OFF_XKD;
    float* hsf = ws + OFF_HSF;
    float* hsb = ws + OFF_HSB;
    float* henc = ws + OFF_HENC;
    unsigned int* erpf = (unsigned int*)(ws + OFF_ERPF);
    unsigned int* erpb = (unsigned int*)(ws + OFF_ERPB);
    unsigned int* drp  = (unsigned int*)(ws + OFF_DRP);
    unsigned short* comb16 = (unsigned short*)(ws + OFF_COMB);
    unsigned short* fb16   = (unsigned short*)(ws + OFF_FB16);
    unsigned short* lfwT   = (unsigned short*)(ws + OFF_LFWT);
    unsigned short* lvwT   = (unsigned short*)(ws + OFF_LVWT);
    float* pmax = ws + OFF_PMAX;
    float* psum = ws + OFF_PSUM;
    float* tlog = ws + OFF_TLOG;
    float* ct_all = ws + OFF_CT;
    float* accum = ws + OFF_ACC;

    bool big = (ws_size >= WS_NEED_BYTES);

    static bool attr_set = false;
    if (!attr_set) {
        hipFuncSetAttribute((const void*)lstm_cvt_fused,
                            hipFuncAttributeMaxDynamicSharedMemorySize, (int)ENC_LDS_BYTES);
        attr_set = true;
    }

    // fused prep: pack weights + all xgate GEMMs (blocks 0-1535 pack, 1536+ xgate)
    hipLaunchKernelGGL(prep_kernel, dim3(3712), dim3(256), 0, stream,
                       erf, erb, dr, erpf, erpb, drp,
                       emb, inp, targ,
                       ekf, ebf, xkf, ekb, ebb, xkb, dk, db, xkd);
    // fused: enc_lstm (blk 0-63) + dec_lstm (blk 64-95) + lfw cvt (96-287) + lvw cvt (288+)
    {
        int nblk = big ? (288 + 12544) : 288;
        hipLaunchKernelGGL(lstm_cvt_fused, dim3(nblk), dim3(512), ENC_LDS_BYTES, stream,
                           xkf, xkb, erpf, erpb, hsf, hsb,
                           xkd, drp, ct_all, comb16,
                           lfw, lfwT, lvw, lvwT);
    }
    hipLaunchKernelGGL(henc_kernel, dim3(256), dim3(256), 0, stream, hsf, hsb, hw, hb, henc);
    hipLaunchKernelGGL(dec_attn, dim3(992), dim3(256), 0, stream,
                       ct_all, sdw, sdb, vat, henc, hsf, hsb, comb16, accum);
    hipLaunchKernelGGL((gemm_bt<0>), dim3(256), dim3(256), 0, stream,
                       comb16, 768, 768, lfwT, 768, 4096, lfb, fb16,
                       (float*)nullptr, (float*)nullptr, 0, (const int*)nullptr, (float*)nullptr);
    if (big)
        hipLaunchKernelGGL((gemm_bt<1>), dim3(3128), dim3(256), 0, stream,
                           fb16, 4096, 4096, lvwT, 4096, 50000, lvb, (unsigned short*)nullptr,
                           pmax, psum, NPART, targ, tlog);
    else
        hipLaunchKernelGGL(gemm_big1, dim3(3128), dim3(256), 0, stream,
                           fb16, 4096, 4096, lvw, 50000, lvb, pmax, psum, NPART, targ, tlog);
    hipLaunchKernelGGL(lse_nll, dim3(1024), dim3(256), 0, stream, pmax, psum, tlog, targ,
                       accum, (float*)d_out);
}